// Round 9
// baseline (156.709 us; speedup 1.0000x reference)
//
#include <hip/hip_runtime.h>

#define HEADS 4
#define DIM_HEAD 32
#define NB 2
#define NC 256
#define HW 4096
#define HIDDEN 128
#define NBH (NB*HEADS)
#define ROWS_TOTAL (NBH*HW)   // 32768

typedef _Float16 f16;
typedef _Float16 f16x8 __attribute__((ext_vector_type(8)));
typedef __fp16 fp16x2 __attribute__((ext_vector_type(2)));
typedef float f32x4 __attribute__((ext_vector_type(4)));

// workspace layout (bytes)
#define XT_OFF   0u                       // f16 [b][s][c256]     4 MB
#define QT_OFF   (4u<<20)                 // f16 [bh][s][d32]     2 MB
#define KT_OFF   (6u<<20)                 // f16 [bh][s][d32]     2 MB
#define VH_OFF   (8u<<20)                 // f16 [bh][d32][s]     2 MB (cols PERMUTED per 32-chunk)
#define HIDT_OFF (10u<<20)                // f16 [b][s][c128]     2 MB
#define WQH_OFF  (12u<<20)                // f16 [384][256]       192 KB
#define WOH_OFF  ((12u<<20) + (256u<<10)) // f16 [256][128]       64 KB
#define PART_OFF (13u<<20)                // f32 [split][33][32768]  25.9 MB (6 splits)
#define NSPLIT 6                          // 1536 blocks = 6/CU (VGPR 48 ->
                                          // thread-capped 8/CU): ONE generation,
                                          // 6 chains/SIMD interleaved

__device__ __forceinline__ f16x8 ldg_f16x8(const f16* p) {
    union { uint4 u; f16x8 v; } t;
    t.u = *reinterpret_cast<const uint4*>(p);
    return t.v;
}
__device__ __forceinline__ unsigned packh2(float a, float b) {
    union { fp16x2 h; unsigned u; } t;
    t.h = __builtin_amdgcn_cvt_pkrtz(a, b);
    return t.u;
}

// ---------------------------------------------------------------------------
// wconv: permute+convert weights to f16.
// ---------------------------------------------------------------------------
__global__ __launch_bounds__(256) void wconv(const float* __restrict__ wqkv,
                                             const float* __restrict__ wout,
                                             f16* __restrict__ wqh,
                                             f16* __restrict__ woh) {
    const int tid = blockIdx.x * 256 + threadIdx.x;
    const float QSCALE = 0.17677669529663687f * 1.4426950408889634f;
    if (tid < 24576) {                       // 384*256/4
        int o_lin = tid >> 6;
        int c4 = (tid & 63) * 4;
        int which = o_lin >> 7, r = o_lin & 127;
        int head = r >> 5, d = r & 31;
        int o_g = head * 96 + d * 3 + which;
        float4 v = *reinterpret_cast<const float4*>(wqkv + o_g * 256 + c4);
        float scl = (which == 0) ? QSCALE : 1.0f;
        uint2 pv;
        pv.x = packh2(v.x * scl, v.y * scl);
        pv.y = packh2(v.z * scl, v.w * scl);
        *reinterpret_cast<uint2*>(wqh + o_lin * 256 + c4) = pv;
    } else if (tid < 24576 + 8192) {         // 256*128/4
        int t2 = tid - 24576;
        float4 v = *reinterpret_cast<const float4*>(wout + t2 * 4);
        uint2 pv;
        pv.x = packh2(v.x, v.y);
        pv.y = packh2(v.z, v.w);
        *reinterpret_cast<uint2*>(woh + t2 * 4) = pv;
    }
}

// ---------------------------------------------------------------------------
// xpose: x[b][c][s] fp32 -> XT[b][s][c] f16 (64x64 LDS-transposed tiles)
// ---------------------------------------------------------------------------
__global__ __launch_bounds__(256) void xpose(const float* __restrict__ x,
                                             f16* __restrict__ xt) {
    __shared__ float T[64][65];
    const int s0 = blockIdx.x * 64, c0 = blockIdx.y * 64, b = blockIdx.z;
    const int t = threadIdx.x;
    #pragma unroll
    for (int i = 0; i < 16; ++i) {
        int e = t + i * 256;
        int c = e >> 6, s = e & 63;
        T[c][s] = x[((size_t)(b * NC + c0 + c)) * HW + s0 + s];
    }
    __syncthreads();
    const int s = t >> 2, cg = (t & 3) * 16;
    unsigned ov[8];
    #pragma unroll
    for (int i = 0; i < 8; ++i)
        ov[i] = packh2(T[cg + 2 * i][s], T[cg + 2 * i + 1][s]);
    f16* dst = xt + ((size_t)(b * HW + s0 + s)) * 256 + c0 + cg;
    *reinterpret_cast<uint4*>(dst)     = make_uint4(ov[0], ov[1], ov[2], ov[3]);
    *reinterpret_cast<uint4*>(dst + 8) = make_uint4(ov[4], ov[5], ov[6], ov[7]);
}

// ---------------------------------------------------------------------------
// qkv_mfma: C[s][o_lin] = XT * WQH^T  (f16 MFMA, K=256).
// VH columns PERMUTED within each 32-aligned chunk so attn's post-QK
// lane-resident exp values are directly the PV B-fragment.
// ---------------------------------------------------------------------------
__global__ __launch_bounds__(256) void qkv_mfma(const f16* __restrict__ xt,
                                                const f16* __restrict__ wqh,
                                                f16* __restrict__ qt,
                                                f16* __restrict__ kt,
                                                f16* __restrict__ vh) {
    const int w = threadIdx.x >> 6, lane = threadIdx.x & 63;
    const int q15 = lane & 15, quad = lane >> 4;
    const int b = blockIdx.z;
    const int sTile = blockIdx.x * 64 + (w & 1) * 32;
    const int oTile = blockIdx.y * 64 + (w >> 1) * 32;
    const f16* A = xt + ((size_t)(b * HW + sTile)) * 256;

    f32x4 acc[2][2];
    #pragma unroll
    for (int i = 0; i < 2; ++i)
        #pragma unroll
        for (int j = 0; j < 2; ++j) acc[i][j] = (f32x4){0.f, 0.f, 0.f, 0.f};

    #pragma unroll
    for (int kc = 0; kc < 256; kc += 32) {
        f16x8 a0 = ldg_f16x8(A + (size_t)q15 * 256 + kc + quad * 8);
        f16x8 a1 = ldg_f16x8(A + (size_t)(16 + q15) * 256 + kc + quad * 8);
        f16x8 b0 = ldg_f16x8(wqh + (size_t)(oTile + q15) * 256 + kc + quad * 8);
        f16x8 b1 = ldg_f16x8(wqh + (size_t)(oTile + 16 + q15) * 256 + kc + quad * 8);
        acc[0][0] = __builtin_amdgcn_mfma_f32_16x16x32_f16(a0, b0, acc[0][0], 0, 0, 0);
        acc[0][1] = __builtin_amdgcn_mfma_f32_16x16x32_f16(a0, b1, acc[0][1], 0, 0, 0);
        acc[1][0] = __builtin_amdgcn_mfma_f32_16x16x32_f16(a1, b0, acc[1][0], 0, 0, 0);
        acc[1][1] = __builtin_amdgcn_mfma_f32_16x16x32_f16(a1, b1, acc[1][1], 0, 0, 0);
    }

    #pragma unroll
    for (int si = 0; si < 2; ++si)
        #pragma unroll
        for (int oj = 0; oj < 2; ++oj) {
            int o_lin = oTile + oj * 16 + q15;
            int which = o_lin >> 7;           // wave-uniform (tiles pure)
            int r = o_lin & 127;
            int head = r >> 5, d = r & 31;
            int bh = b * HEADS + head;
            int s2 = sTile + si * 16 + quad * 4;
            if (which == 2) {
                uint2 pv;
                pv.x = packh2(acc[si][oj][0], acc[si][oj][1]);
                pv.y = packh2(acc[si][oj][2], acc[si][oj][3]);
                int vcol = sTile + quad * 8 + si * 4;
                *reinterpret_cast<uint2*>(vh + ((size_t)(bh * 32 + d)) * HW + vcol) = pv;
            } else {
                f16* dst = (which == 0 ? qt : kt) + (size_t)bh * HW * 32;
                #pragma unroll
                for (int r2 = 0; r2 < 4; ++r2)
                    dst[(size_t)(s2 + r2) * 32 + d] = (f16)acc[si][oj][r2];
            }
        }
}

// ---------------------------------------------------------------------------
// attn_mfma: MFMA flash attention, no-max softmax, split-K over j (6 splits),
// explicit next-chunk prefetch.  Per wave: 32 q-rows x split-span keys.
// Zero LDS; VH permutation makes exp values the PV B-fragment directly.
// r9 CONCURRENCY FIX: r8 found the runtime span kills the unroll -> VGPR 48
// (was 164), no spill, occupancy 28%, attn 59->52us.  At VGPR 48 residency
// is thread-capped (8 blocks/CU), so NSPLIT=6 -> 1536 blocks = 6/CU in ONE
// generation: 6 chains/SIMD interleaved (was 3) at constant total issue work
// (6 x ~21 chunks = 3 x 43).  Splits stay RUNTIME-computed (21+(split<2)
// chunks) to preserve the no-unroll low-VGPR form.
// XCD-AFFINITY: 192 blocks/XCD = 6 (split,bh) combos x 32 q-blocks (~1MB
// K/V per XCD L2; FETCH=unique verified r5/r8).
// NO launch_bounds min-occupancy arg (r2/r4: any hint -> spill storm).
// ---------------------------------------------------------------------------
__global__ __launch_bounds__(256) void attn_mfma(const f16* __restrict__ qt,
                                                 const f16* __restrict__ kt,
                                                 const f16* __restrict__ vh,
                                                 float* __restrict__ part) {
    const int w    = threadIdx.x >> 6;
    const int lane = threadIdx.x & 63;
    const int q15  = lane & 15;
    const int quad = lane >> 4;

    const int L    = blockIdx.x;          // 0..1535
    const int xcd  = L & 7;               // dispatch round-robin -> XCD id
    const int slot = L >> 3;              // 0..191 within XCD
    const int combo = xcd * 6 + (slot >> 5);   // 0..47 = (split,bh)
    const int qblk  = slot & 31;
    const int bh    = combo & 7;
    const int split = combo >> 3;              // 0..5
    const int qbase = (qblk * 4 + w) * 32;

    const f16* Qb = qt + (size_t)bh * HW * 32;
    const f16* Kb = kt + (size_t)bh * HW * 32;
    const f16* Vb = vh + (size_t)bh * 32 * HW;

    f16x8 qf0 = ldg_f16x8(Qb + (size_t)(qbase + q15) * 32 + quad * 8);
    f16x8 qf1 = ldg_f16x8(Qb + (size_t)(qbase + 16 + q15) * 32 + quad * 8);

    f32x4 acc[2][2];
    #pragma unroll
    for (int a = 0; a < 2; ++a)
        #pragma unroll
        for (int b2 = 0; b2 < 2; ++b2)
            acc[a][b2] = (f32x4){0.f, 0.f, 0.f, 0.f};
    float l0 = 0.f, l1 = 0.f;

    // splits: chunks = 21 + (split<2) -> 22,22,21,21,21,21 (sum 128 = 4096 keys)
    // j0 = 32 * (21*split + min(split,2))
    const int j0   = 672 * split + 32 * (split < 2 ? split : 2);
    const int span = 672 + 32 * (split < 2);

    f16x8 kf0 = ldg_f16x8(Kb + (size_t)(j0 + q15) * 32 + quad * 8);
    f16x8 kf1 = ldg_f16x8(Kb + (size_t)(j0 + 16 + q15) * 32 + quad * 8);
    f16x8 vf0 = ldg_f16x8(Vb + (size_t)q15 * HW + j0 + quad * 8);
    f16x8 vf1 = ldg_f16x8(Vb + (size_t)(16 + q15) * HW + j0 + quad * 8);

    for (int jc = 0; jc < span; jc += 32) {
        const int jn = j0 + jc + 32;   // prefetch (last iter reads past span:
                                       // lands in adjacent ws region, unused)
        f16x8 nk0 = ldg_f16x8(Kb + (size_t)(jn + q15) * 32 + quad * 8);
        f16x8 nk1 = ldg_f16x8(Kb + (size_t)(jn + 16 + q15) * 32 + quad * 8);
        f16x8 nv0 = ldg_f16x8(Vb + (size_t)q15 * HW + jn + quad * 8);
        f16x8 nv1 = ldg_f16x8(Vb + (size_t)(16 + q15) * HW + jn + quad * 8);

        const f32x4 z = {0.f, 0.f, 0.f, 0.f};
        #pragma unroll
        for (int qb = 0; qb < 2; ++qb) {
            f16x8 qf = qb ? qf1 : qf0;
            // s0[r] = S[key = quad*4+r][q=q15], s1[r] = S[key = 16+quad*4+r][q]
            f32x4 s0 = __builtin_amdgcn_mfma_f32_16x16x32_f16(kf0, qf, z, 0, 0, 0);
            f32x4 s1 = __builtin_amdgcn_mfma_f32_16x16x32_f16(kf1, qf, z, 0, 0, 0);
            float e[8];
            #pragma unroll
            for (int r = 0; r < 4; ++r) {
                e[r]     = __builtin_amdgcn_exp2f(s0[r]);
                e[4 + r] = __builtin_amdgcn_exp2f(s1[r]);
            }
            float ls = (e[0] + e[1]) + (e[2] + e[3]) + (e[4] + e[5]) + (e[6] + e[7]);
            if (qb) l1 += ls; else l0 += ls;
            // VH column permutation makes this lane's 8 exp values exactly
            // B[k = quad*8 + 0..7][q=q15] for the PV MFMA: pack and go.
            union { unsigned u[4]; f16x8 v; } pu;
            pu.u[0] = packh2(e[0], e[1]);
            pu.u[1] = packh2(e[2], e[3]);
            pu.u[2] = packh2(e[4], e[5]);
            pu.u[3] = packh2(e[6], e[7]);
            acc[qb][0] = __builtin_amdgcn_mfma_f32_16x16x32_f16(vf0, pu.v, acc[qb][0], 0, 0, 0);
            acc[qb][1] = __builtin_amdgcn_mfma_f32_16x16x32_f16(vf1, pu.v, acc[qb][1], 0, 0, 0);
        }
        kf0 = nk0; kf1 = nk1; vf0 = nv0; vf1 = nv1;
    }

    float* P = part + (size_t)split * 33 * ROWS_TOTAL;
    #pragma unroll
    for (int qb = 0; qb < 2; ++qb) {
        float lv = qb ? l1 : l0;
        lv += __shfl_xor(lv, 16, 64);
        lv += __shfl_xor(lv, 32, 64);
        const int grow = bh * HW + qbase + qb * 16 + q15;
        if (quad == 0) P[grow] = lv;
        #pragma unroll
        for (int t = 0; t < 2; ++t)
            #pragma unroll
            for (int r = 0; r < 4; ++r) {
                int d = t * 16 + quad * 4 + r;
                P[(size_t)(1 + d) * ROWS_TOTAL + grow] = acc[qb][t][r];
            }
    }
}

// ---------------------------------------------------------------------------
// attn_merge: sum NSPLIT additive splits, normalize, write HIDT f16.
// thread = (grow, dquad): 131072 threads / 512 blocks, 54 independent 4B
// loads + one coalesced 16B write each (r7 fix: was 64us at 128 blocks).
// ---------------------------------------------------------------------------
__global__ __launch_bounds__(256) void attn_merge(const float* __restrict__ part,
                                                  f16* __restrict__ hidt) {
    const int t = blockIdx.x * 256 + threadIdx.x;      // 0..131071
    const int grow = t >> 2;                           // 0..32767
    const int dq   = t & 3;                            // 0..3 (8 d values each)
    float l = 0.f;
    #pragma unroll
    for (int sp = 0; sp < NSPLIT; ++sp)
        l += part[(size_t)sp * 33 * ROWS_TOTAL + grow];
    const float inv = 1.0f / l;
    const int bh = grow >> 12, s = grow & 4095;
    const int b = bh >> 2, h = bh & 3;

    unsigned ov[4];
    #pragma unroll
    for (int i = 0; i < 4; ++i) {
        const int d2 = dq * 4 + i;
        float o0 = 0.f, o1 = 0.f;
        #pragma unroll
        for (int sp = 0; sp < NSPLIT; ++sp) {
            const float* P = part + (size_t)sp * 33 * ROWS_TOTAL + grow;
            o0 += P[(size_t)(1 + 2 * d2) * ROWS_TOTAL];
            o1 += P[(size_t)(2 + 2 * d2) * ROWS_TOTAL];
        }
        ov[i] = packh2(o0 * inv, o1 * inv);
    }
    f16* dst = hidt + ((size_t)(b * HW + s)) * 128 + h * 32 + dq * 8;
    *reinterpret_cast<uint4*>(dst) = make_uint4(ov[0], ov[1], ov[2], ov[3]);
}

// ---------------------------------------------------------------------------
// outp_mfma: out[b][o][s] = HIDT * WOH^T + bias  (f16 MFMA, K=128, fp32 out)
// ---------------------------------------------------------------------------
__global__ __launch_bounds__(256) void outp_mfma(const f16* __restrict__ hidt,
                                                 const f16* __restrict__ woh,
                                                 const float* __restrict__ bout,
                                                 float* __restrict__ out) {
    const int w = threadIdx.x >> 6, lane = threadIdx.x & 63;
    const int q15 = lane & 15, quad = lane >> 4;
    const int b = blockIdx.z;
    const int sTile = blockIdx.x * 64 + (w & 1) * 32;
    const int oTile = blockIdx.y * 64 + (w >> 1) * 32;
    const f16* A = hidt + ((size_t)(b * HW + sTile)) * 128;

    f32x4 acc[2][2];
    #pragma unroll
    for (int i = 0; i < 2; ++i)
        #pragma unroll
        for (int j = 0; j < 2; ++j) acc[i][j] = (f32x4){0.f, 0.f, 0.f, 0.f};

    #pragma unroll
    for (int kc = 0; kc < 128; kc += 32) {
        f16x8 a0 = ldg_f16x8(A + (size_t)q15 * 128 + kc + quad * 8);
        f16x8 a1 = ldg_f16x8(A + (size_t)(16 + q15) * 128 + kc + quad * 8);
        f16x8 b0 = ldg_f16x8(woh + (size_t)(oTile + q15) * 128 + kc + quad * 8);
        f16x8 b1 = ldg_f16x8(woh + (size_t)(oTile + 16 + q15) * 128 + kc + quad * 8);
        acc[0][0] = __builtin_amdgcn_mfma_f32_16x16x32_f16(a0, b0, acc[0][0], 0, 0, 0);
        acc[0][1] = __builtin_amdgcn_mfma_f32_16x16x32_f16(a0, b1, acc[0][1], 0, 0, 0);
        acc[1][0] = __builtin_amdgcn_mfma_f32_16x16x32_f16(a1, b0, acc[1][0], 0, 0, 0);
        acc[1][1] = __builtin_amdgcn_mfma_f32_16x16x32_f16(a1, b1, acc[1][1], 0, 0, 0);
    }

    #pragma unroll
    for (int oj = 0; oj < 2; ++oj) {
        const int o = oTile + oj * 16 + q15;
        const float bias = bout[o];
        #pragma unroll
        for (int si = 0; si < 2; ++si) {
            const int s2 = sTile + si * 16 + quad * 4;
            float4 v = make_float4(acc[si][oj][0] + bias, acc[si][oj][1] + bias,
                                   acc[si][oj][2] + bias, acc[si][oj][3] + bias);
            *reinterpret_cast<float4*>(out + ((size_t)(b * NC + o)) * HW + s2) = v;
        }
    }
}

// ---------------------------------------------------------------------------
extern "C" void kernel_launch(void* const* d_in, const int* in_sizes, int n_in,
                              void* d_out, int out_size, void* d_ws, size_t ws_size,
                              hipStream_t stream) {
    const float* x    = (const float*)d_in[0];
    const float* wqkv = (const float*)d_in[1];
    const float* wout = (const float*)d_in[2];
    const float* bout = (const float*)d_in[3];
    float* out = (float*)d_out;
    char* wsb  = (char*)d_ws;

    f16*   XT   = (f16*)(wsb + XT_OFF);
    f16*   QT   = (f16*)(wsb + QT_OFF);
    f16*   KT   = (f16*)(wsb + KT_OFF);
    f16*   VH   = (f16*)(wsb + VH_OFF);
    f16*   HIDT = (f16*)(wsb + HIDT_OFF);
    f16*   WQH  = (f16*)(wsb + WQH_OFF);
    f16*   WOH  = (f16*)(wsb + WOH_OFF);
    float* PART = (float*)(wsb + PART_OFF);

    wconv    <<<dim3(128), 256, 0, stream>>>(wqkv, wout, WQH, WOH);
    xpose    <<<dim3(64, 4, NB), 256, 0, stream>>>(x, XT);
    qkv_mfma <<<dim3(64, 6, NB), 256, 0, stream>>>(XT, WQH, QT, KT, VH);
    attn_mfma<<<dim3(1536), 256, 0, stream>>>(QT, KT, VH, PART);
    attn_merge<<<dim3(512), 256, 0, stream>>>(PART, HIDT);
    outp_mfma<<<dim3(64, 4, NB), 256, 0, stream>>>(HIDT, WOH, bout, out);
}

// Round 10
// 142.605 us; speedup vs baseline: 1.0989x; 1.0989x over previous
//
#include <hip/hip_runtime.h>

#define HEADS 4
#define DIM_HEAD 32
#define NB 2
#define NC 256
#define HW 4096
#define HIDDEN 128
#define NBH (NB*HEADS)
#define ROWS_TOTAL (NBH*HW)   // 32768

typedef _Float16 f16;
typedef _Float16 f16x8 __attribute__((ext_vector_type(8)));
typedef __fp16 fp16x2 __attribute__((ext_vector_type(2)));
typedef float f32x4 __attribute__((ext_vector_type(4)));

// workspace layout (bytes)
#define XT_OFF   0u                       // f16 [b][s][c256]     4 MB
#define QT_OFF   (4u<<20)                 // f16 [bh][s][d32]     2 MB
#define KT_OFF   (6u<<20)                 // f16 [bh][s][d32]     2 MB
#define VH_OFF   (8u<<20)                 // f16 [bh][d32][s]     2 MB (cols PERMUTED per 32-chunk)
#define HIDT_OFF (10u<<20)                // f16 [b][s][c128]     2 MB
#define WQH_OFF  (12u<<20)                // f16 [384][256]       192 KB
#define WOH_OFF  ((12u<<20) + (256u<<10)) // f16 [256][128]       64 KB
#define PART_OFF (13u<<20)                // f32 [split][33][32768]  13 MB (3 splits)
#define NSPLIT 3                          // 768 blocks = 3/CU: ONE generation
                                          // (r8-proven best geometry; r9 showed
                                          // 6/CU REGRESSES: queue contention)

__device__ __forceinline__ f16x8 ldg_f16x8(const f16* p) {
    union { uint4 u; f16x8 v; } t;
    t.u = *reinterpret_cast<const uint4*>(p);
    return t.v;
}
__device__ __forceinline__ unsigned packh2(float a, float b) {
    union { fp16x2 h; unsigned u; } t;
    t.h = __builtin_amdgcn_cvt_pkrtz(a, b);
    return t.u;
}

// ---------------------------------------------------------------------------
// wconv: permute+convert weights to f16.
// ---------------------------------------------------------------------------
__global__ __launch_bounds__(256) void wconv(const float* __restrict__ wqkv,
                                             const float* __restrict__ wout,
                                             f16* __restrict__ wqh,
                                             f16* __restrict__ woh) {
    const int tid = blockIdx.x * 256 + threadIdx.x;
    const float QSCALE = 0.17677669529663687f * 1.4426950408889634f;
    if (tid < 24576) {                       // 384*256/4
        int o_lin = tid >> 6;
        int c4 = (tid & 63) * 4;
        int which = o_lin >> 7, r = o_lin & 127;
        int head = r >> 5, d = r & 31;
        int o_g = head * 96 + d * 3 + which;
        float4 v = *reinterpret_cast<const float4*>(wqkv + o_g * 256 + c4);
        float scl = (which == 0) ? QSCALE : 1.0f;
        uint2 pv;
        pv.x = packh2(v.x * scl, v.y * scl);
        pv.y = packh2(v.z * scl, v.w * scl);
        *reinterpret_cast<uint2*>(wqh + o_lin * 256 + c4) = pv;
    } else if (tid < 24576 + 8192) {         // 256*128/4
        int t2 = tid - 24576;
        float4 v = *reinterpret_cast<const float4*>(wout + t2 * 4);
        uint2 pv;
        pv.x = packh2(v.x, v.y);
        pv.y = packh2(v.z, v.w);
        *reinterpret_cast<uint2*>(woh + t2 * 4) = pv;
    }
}

// ---------------------------------------------------------------------------
// xpose: x[b][c][s] fp32 -> XT[b][s][c] f16 (64x64 LDS-transposed tiles)
// ---------------------------------------------------------------------------
__global__ __launch_bounds__(256) void xpose(const float* __restrict__ x,
                                             f16* __restrict__ xt) {
    __shared__ float T[64][65];
    const int s0 = blockIdx.x * 64, c0 = blockIdx.y * 64, b = blockIdx.z;
    const int t = threadIdx.x;
    #pragma unroll
    for (int i = 0; i < 16; ++i) {
        int e = t + i * 256;
        int c = e >> 6, s = e & 63;
        T[c][s] = x[((size_t)(b * NC + c0 + c)) * HW + s0 + s];
    }
    __syncthreads();
    const int s = t >> 2, cg = (t & 3) * 16;
    unsigned ov[8];
    #pragma unroll
    for (int i = 0; i < 8; ++i)
        ov[i] = packh2(T[cg + 2 * i][s], T[cg + 2 * i + 1][s]);
    f16* dst = xt + ((size_t)(b * HW + s0 + s)) * 256 + c0 + cg;
    *reinterpret_cast<uint4*>(dst)     = make_uint4(ov[0], ov[1], ov[2], ov[3]);
    *reinterpret_cast<uint4*>(dst + 8) = make_uint4(ov[4], ov[5], ov[6], ov[7]);
}

// ---------------------------------------------------------------------------
// qkv_mfma: C[s][o_lin] = XT * WQH^T  (f16 MFMA, K=256).
// VH columns PERMUTED within each 32-aligned chunk so attn's post-QK
// lane-resident exp values are directly the PV B-fragment.
// ---------------------------------------------------------------------------
__global__ __launch_bounds__(256) void qkv_mfma(const f16* __restrict__ xt,
                                                const f16* __restrict__ wqh,
                                                f16* __restrict__ qt,
                                                f16* __restrict__ kt,
                                                f16* __restrict__ vh) {
    const int w = threadIdx.x >> 6, lane = threadIdx.x & 63;
    const int q15 = lane & 15, quad = lane >> 4;
    const int b = blockIdx.z;
    const int sTile = blockIdx.x * 64 + (w & 1) * 32;
    const int oTile = blockIdx.y * 64 + (w >> 1) * 32;
    const f16* A = xt + ((size_t)(b * HW + sTile)) * 256;

    f32x4 acc[2][2];
    #pragma unroll
    for (int i = 0; i < 2; ++i)
        #pragma unroll
        for (int j = 0; j < 2; ++j) acc[i][j] = (f32x4){0.f, 0.f, 0.f, 0.f};

    #pragma unroll
    for (int kc = 0; kc < 256; kc += 32) {
        f16x8 a0 = ldg_f16x8(A + (size_t)q15 * 256 + kc + quad * 8);
        f16x8 a1 = ldg_f16x8(A + (size_t)(16 + q15) * 256 + kc + quad * 8);
        f16x8 b0 = ldg_f16x8(wqh + (size_t)(oTile + q15) * 256 + kc + quad * 8);
        f16x8 b1 = ldg_f16x8(wqh + (size_t)(oTile + 16 + q15) * 256 + kc + quad * 8);
        acc[0][0] = __builtin_amdgcn_mfma_f32_16x16x32_f16(a0, b0, acc[0][0], 0, 0, 0);
        acc[0][1] = __builtin_amdgcn_mfma_f32_16x16x32_f16(a0, b1, acc[0][1], 0, 0, 0);
        acc[1][0] = __builtin_amdgcn_mfma_f32_16x16x32_f16(a1, b0, acc[1][0], 0, 0, 0);
        acc[1][1] = __builtin_amdgcn_mfma_f32_16x16x32_f16(a1, b1, acc[1][1], 0, 0, 0);
    }

    #pragma unroll
    for (int si = 0; si < 2; ++si)
        #pragma unroll
        for (int oj = 0; oj < 2; ++oj) {
            int o_lin = oTile + oj * 16 + q15;
            int which = o_lin >> 7;           // wave-uniform (tiles pure)
            int r = o_lin & 127;
            int head = r >> 5, d = r & 31;
            int bh = b * HEADS + head;
            int s2 = sTile + si * 16 + quad * 4;
            if (which == 2) {
                uint2 pv;
                pv.x = packh2(acc[si][oj][0], acc[si][oj][1]);
                pv.y = packh2(acc[si][oj][2], acc[si][oj][3]);
                int vcol = sTile + quad * 8 + si * 4;
                *reinterpret_cast<uint2*>(vh + ((size_t)(bh * 32 + d)) * HW + vcol) = pv;
            } else {
                f16* dst = (which == 0 ? qt : kt) + (size_t)bh * HW * 32;
                #pragma unroll
                for (int r2 = 0; r2 < 4; ++r2)
                    dst[(size_t)(s2 + r2) * 32 + d] = (f16)acc[si][oj][r2];
            }
        }
}

// ---------------------------------------------------------------------------
// attn_mfma: MFMA flash attention, no-max softmax, split-K over j (3 splits).
// Zero LDS; VH permutation makes exp values the PV B-fragment directly.
// r10 LOOP RESTRUCTURE: r8/r9 data shows the per-chunk stall is the
// register-rotation wait (loads issued at iter top, vmcnt(0) forced by the
// kf=nk rotation ~300cyc later -> latency never hidden; extra waves only
// lengthen the exposed queue, r9's 6/CU regression).  Now 2 chunks/iter
// with alternating A/B register sets: A's loads are issued one full
// CHUNK+LDKV (~2900cyc) before consumption, and the 16 rotation movs are
// gone.  Splits 22/21/21 chunks of 64 keys (1408/1344/1344), runtime span
// -> compiler keeps the rolled low-VGPR form (r8: VGPR 48, occupancy 28%).
// Geometry unchanged from r8: NSPLIT=3, 768 blocks = 3/CU, one generation.
// XCD-AFFINITY: 96 blocks/XCD = 3 (split,bh) combos x 32 q-blocks.
// NO launch_bounds min-occupancy arg (r2/r4: any hint -> spill storm).
// ---------------------------------------------------------------------------
#define MFMA16(A,B,C) __builtin_amdgcn_mfma_f32_16x16x32_f16(A,B,C,0,0,0)

#define LDKV(kd0,kd1,vd0,vd1,J)                                          \
    kd0 = ldg_f16x8(Kb + (size_t)((J) + q15) * 32 + quad * 8);           \
    kd1 = ldg_f16x8(Kb + (size_t)((J) + 16 + q15) * 32 + quad * 8);      \
    vd0 = ldg_f16x8(Vb + (size_t)q15 * HW + (J) + quad * 8);             \
    vd1 = ldg_f16x8(Vb + (size_t)(16 + q15) * HW + (J) + quad * 8);

#define CHUNK(kf0_,kf1_,vf0_,vf1_)                                       \
    {                                                                    \
        const f32x4 z = {0.f, 0.f, 0.f, 0.f};                            \
        f32x4 s0a = MFMA16(kf0_, qf0, z);                                \
        f32x4 s1a = MFMA16(kf1_, qf0, z);                                \
        f32x4 s0b = MFMA16(kf0_, qf1, z);                                \
        f32x4 s1b = MFMA16(kf1_, qf1, z);                                \
        float ea[8], eb[8];                                              \
        _Pragma("unroll")                                                \
        for (int r = 0; r < 4; ++r) {                                    \
            ea[r]   = __builtin_amdgcn_exp2f(s0a[r]);                    \
            ea[4+r] = __builtin_amdgcn_exp2f(s1a[r]);                    \
            eb[r]   = __builtin_amdgcn_exp2f(s0b[r]);                    \
            eb[4+r] = __builtin_amdgcn_exp2f(s1b[r]);                    \
        }                                                                \
        l0 += (ea[0]+ea[1])+(ea[2]+ea[3])+(ea[4]+ea[5])+(ea[6]+ea[7]);   \
        l1 += (eb[0]+eb[1])+(eb[2]+eb[3])+(eb[4]+eb[5])+(eb[6]+eb[7]);   \
        union { unsigned u[4]; f16x8 v; } pa, pb;                        \
        pa.u[0] = packh2(ea[0], ea[1]); pa.u[1] = packh2(ea[2], ea[3]);  \
        pa.u[2] = packh2(ea[4], ea[5]); pa.u[3] = packh2(ea[6], ea[7]);  \
        pb.u[0] = packh2(eb[0], eb[1]); pb.u[1] = packh2(eb[2], eb[3]);  \
        pb.u[2] = packh2(eb[4], eb[5]); pb.u[3] = packh2(eb[6], eb[7]);  \
        acc[0][0] = MFMA16(vf0_, pa.v, acc[0][0]);                       \
        acc[0][1] = MFMA16(vf1_, pa.v, acc[0][1]);                       \
        acc[1][0] = MFMA16(vf0_, pb.v, acc[1][0]);                       \
        acc[1][1] = MFMA16(vf1_, pb.v, acc[1][1]);                       \
    }

__global__ __launch_bounds__(256) void attn_mfma(const f16* __restrict__ qt,
                                                 const f16* __restrict__ kt,
                                                 const f16* __restrict__ vh,
                                                 float* __restrict__ part) {
    const int w    = threadIdx.x >> 6;
    const int lane = threadIdx.x & 63;
    const int q15  = lane & 15;
    const int quad = lane >> 4;

    const int L    = blockIdx.x;          // 0..767
    const int xcd  = L & 7;               // dispatch round-robin -> XCD id
    const int slot = L >> 3;              // 0..95 within XCD
    const int combo = xcd * 3 + (slot >> 5);   // 0..23 = (split,bh)
    const int qblk  = slot & 31;
    const int bh    = combo & 7;
    const int split = combo >> 3;              // 0..2
    const int qbase = (qblk * 4 + w) * 32;

    const f16* Qb = qt + (size_t)bh * HW * 32;
    const f16* Kb = kt + (size_t)bh * HW * 32;
    const f16* Vb = vh + (size_t)bh * 32 * HW;

    f16x8 qf0 = ldg_f16x8(Qb + (size_t)(qbase + q15) * 32 + quad * 8);
    f16x8 qf1 = ldg_f16x8(Qb + (size_t)(qbase + 16 + q15) * 32 + quad * 8);

    f32x4 acc[2][2];
    #pragma unroll
    for (int a = 0; a < 2; ++a)
        #pragma unroll
        for (int b2 = 0; b2 < 2; ++b2)
            acc[a][b2] = (f32x4){0.f, 0.f, 0.f, 0.f};
    float l0 = 0.f, l1 = 0.f;

    // splits: 22/21/21 double-chunks of 64 keys -> spans 1408/1344/1344
    const int j0   = split * 1344 + (split ? 64 : 0);
    const int span = 1344 + (split == 0 ? 64 : 0);

    f16x8 ka0, ka1, va0, va1, kb0, kb1, vb0, vb1;
    LDKV(ka0, ka1, va0, va1, j0);
    LDKV(kb0, kb1, vb0, vb1, j0 + 32);

    for (int jc = 0; jc < span; jc += 64) {
        CHUNK(ka0, ka1, va0, va1);
        LDKV(ka0, ka1, va0, va1, j0 + jc + 64);   // last-iter prefetch reads
        CHUNK(kb0, kb1, vb0, vb1);                // past span: valid ws mem,
        LDKV(kb0, kb1, vb0, vb1, j0 + jc + 96);   // values unused
    }

    float* P = part + (size_t)split * 33 * ROWS_TOTAL;
    #pragma unroll
    for (int qb = 0; qb < 2; ++qb) {
        float lv = qb ? l1 : l0;
        lv += __shfl_xor(lv, 16, 64);
        lv += __shfl_xor(lv, 32, 64);
        const int grow = bh * HW + qbase + qb * 16 + q15;
        if (quad == 0) P[grow] = lv;
        #pragma unroll
        for (int t = 0; t < 2; ++t)
            #pragma unroll
            for (int r = 0; r < 4; ++r) {
                int d = t * 16 + quad * 4 + r;
                P[(size_t)(1 + d) * ROWS_TOTAL + grow] = acc[qb][t][r];
            }
    }
}

// ---------------------------------------------------------------------------
// attn_merge: sum NSPLIT additive splits, normalize, write HIDT f16.
// thread = (grow, dquad): 131072 threads / 512 blocks, 27 independent 4B
// loads + one coalesced 16B write each (r7 fix: was 64us at 128 blocks).
// ---------------------------------------------------------------------------
__global__ __launch_bounds__(256) void attn_merge(const float* __restrict__ part,
                                                  f16* __restrict__ hidt) {
    const int t = blockIdx.x * 256 + threadIdx.x;      // 0..131071
    const int grow = t >> 2;                           // 0..32767
    const int dq   = t & 3;                            // 0..3 (8 d values each)
    float l = 0.f;
    #pragma unroll
    for (int sp = 0; sp < NSPLIT; ++sp)
        l += part[(size_t)sp * 33 * ROWS_TOTAL + grow];
    const float inv = 1.0f / l;
    const int bh = grow >> 12, s = grow & 4095;
    const int b = bh >> 2, h = bh & 3;

    unsigned ov[4];
    #pragma unroll
    for (int i = 0; i < 4; ++i) {
        const int d2 = dq * 4 + i;
        float o0 = 0.f, o1 = 0.f;
        #pragma unroll
        for (int sp = 0; sp < NSPLIT; ++sp) {
            const float* P = part + (size_t)sp * 33 * ROWS_TOTAL + grow;
            o0 += P[(size_t)(1 + 2 * d2) * ROWS_TOTAL];
            o1 += P[(size_t)(2 + 2 * d2) * ROWS_TOTAL];
        }
        ov[i] = packh2(o0 * inv, o1 * inv);
    }
    f16* dst = hidt + ((size_t)(b * HW + s)) * 128 + h * 32 + dq * 8;
    *reinterpret_cast<uint4*>(dst) = make_uint4(ov[0], ov[1], ov[2], ov[3]);
}

// ---------------------------------------------------------------------------
// outp_mfma: out[b][o][s] = HIDT * WOH^T + bias  (f16 MFMA, K=128, fp32 out)
// ---------------------------------------------------------------------------
__global__ __launch_bounds__(256) void outp_mfma(const f16* __restrict__ hidt,
                                                 const f16* __restrict__ woh,
                                                 const float* __restrict__ bout,
                                                 float* __restrict__ out) {
    const int w = threadIdx.x >> 6, lane = threadIdx.x & 63;
    const int q15 = lane & 15, quad = lane >> 4;
    const int b = blockIdx.z;
    const int sTile = blockIdx.x * 64 + (w & 1) * 32;
    const int oTile = blockIdx.y * 64 + (w >> 1) * 32;
    const f16* A = hidt + ((size_t)(b * HW + sTile)) * 128;

    f32x4 acc[2][2];
    #pragma unroll
    for (int i = 0; i < 2; ++i)
        #pragma unroll
        for (int j = 0; j < 2; ++j) acc[i][j] = (f32x4){0.f, 0.f, 0.f, 0.f};

    #pragma unroll
    for (int kc = 0; kc < 128; kc += 32) {
        f16x8 a0 = ldg_f16x8(A + (size_t)q15 * 128 + kc + quad * 8);
        f16x8 a1 = ldg_f16x8(A + (size_t)(16 + q15) * 128 + kc + quad * 8);
        f16x8 b0 = ldg_f16x8(woh + (size_t)(oTile + q15) * 128 + kc + quad * 8);
        f16x8 b1 = ldg_f16x8(woh + (size_t)(oTile + 16 + q15) * 128 + kc + quad * 8);
        acc[0][0] = __builtin_amdgcn_mfma_f32_16x16x32_f16(a0, b0, acc[0][0], 0, 0, 0);
        acc[0][1] = __builtin_amdgcn_mfma_f32_16x16x32_f16(a0, b1, acc[0][1], 0, 0, 0);
        acc[1][0] = __builtin_amdgcn_mfma_f32_16x16x32_f16(a1, b0, acc[1][0], 0, 0, 0);
        acc[1][1] = __builtin_amdgcn_mfma_f32_16x16x32_f16(a1, b1, acc[1][1], 0, 0, 0);
    }

    #pragma unroll
    for (int oj = 0; oj < 2; ++oj) {
        const int o = oTile + oj * 16 + q15;
        const float bias = bout[o];
        #pragma unroll
        for (int si = 0; si < 2; ++si) {
            const int s2 = sTile + si * 16 + quad * 4;
            float4 v = make_float4(acc[si][oj][0] + bias, acc[si][oj][1] + bias,
                                   acc[si][oj][2] + bias, acc[si][oj][3] + bias);
            *reinterpret_cast<float4*>(out + ((size_t)(b * NC + o)) * HW + s2) = v;
        }
    }
}

// ---------------------------------------------------------------------------
extern "C" void kernel_launch(void* const* d_in, const int* in_sizes, int n_in,
                              void* d_out, int out_size, void* d_ws, size_t ws_size,
                              hipStream_t stream) {
    const float* x    = (const float*)d_in[0];
    const float* wqkv = (const float*)d_in[1];
    const float* wout = (const float*)d_in[2];
    const float* bout = (const float*)d_in[3];
    float* out = (float*)d_out;
    char* wsb  = (char*)d_ws;

    f16*   XT   = (f16*)(wsb + XT_OFF);
    f16*   QT   = (f16*)(wsb + QT_OFF);
    f16*   KT   = (f16*)(wsb + KT_OFF);
    f16*   VH   = (f16*)(wsb + VH_OFF);
    f16*   HIDT = (f16*)(wsb + HIDT_OFF);
    f16*   WQH  = (f16*)(wsb + WQH_OFF);
    f16*   WOH  = (f16*)(wsb + WOH_OFF);
    float* PART = (float*)(wsb + PART_OFF);

    wconv    <<<dim3(128), 256, 0, stream>>>(wqkv, wout, WQH, WOH);
    xpose    <<<dim3(64, 4, NB), 256, 0, stream>>>(x, XT);
    qkv_mfma <<<dim3(64, 6, NB), 256, 0, stream>>>(XT, WQH, QT, KT, VH);
    attn_mfma<<<dim3(768), 256, 0, stream>>>(QT, KT, VH, PART);
    attn_merge<<<dim3(512), 256, 0, stream>>>(PART, HIDT);
    outp_mfma<<<dim3(64, 4, NB), 256, 0, stream>>>(HIDT, WOH, bout, out);
}

// Round 11
// 128.383 us; speedup vs baseline: 1.2206x; 1.1108x over previous
//
#include <hip/hip_runtime.h>

#define HEADS 4
#define DIM_HEAD 32
#define NB 2
#define NC 256
#define HW 4096
#define HIDDEN 128
#define NBH (NB*HEADS)
#define ROWS_TOTAL (NBH*HW)   // 32768

typedef _Float16 f16;
typedef _Float16 f16x8 __attribute__((ext_vector_type(8)));
typedef __fp16 fp16x2 __attribute__((ext_vector_type(2)));
typedef float f32x4 __attribute__((ext_vector_type(4)));

// workspace layout (bytes)
#define XT_OFF   0u                       // f16 [b][s][c256]     4 MB
#define QT_OFF   (4u<<20)                 // f16 [bh][s][d32]     2 MB
#define KT_OFF   (6u<<20)                 // f16 [bh][s][d32]     2 MB
#define VH_OFF   (8u<<20)                 // f16 [bh][s/32][d32][32]  2 MB  (CHUNK-TILED, cols permuted)
#define HIDT_OFF (10u<<20)                // f16 [b][s][c128]     2 MB
#define WQH_OFF  (12u<<20)                // f16 [384][256]       192 KB
#define WOH_OFF  ((12u<<20) + (256u<<10)) // f16 [256][128]       64 KB
#define PART_OFF (13u<<20)                // f32 [split][33][32768]  13 MB (3 splits)
#define NSPLIT 3                          // 768 blocks = 3/CU: ONE generation
                                          // (r8-proven; r9 showed 6/CU regresses)

__device__ __forceinline__ f16x8 ldg_f16x8(const f16* p) {
    union { uint4 u; f16x8 v; } t;
    t.u = *reinterpret_cast<const uint4*>(p);
    return t.v;
}
__device__ __forceinline__ unsigned packh2(float a, float b) {
    union { fp16x2 h; unsigned u; } t;
    t.h = __builtin_amdgcn_cvt_pkrtz(a, b);
    return t.u;
}

// ---------------------------------------------------------------------------
// wconv: permute+convert weights to f16.
// ---------------------------------------------------------------------------
__global__ __launch_bounds__(256) void wconv(const float* __restrict__ wqkv,
                                             const float* __restrict__ wout,
                                             f16* __restrict__ wqh,
                                             f16* __restrict__ woh) {
    const int tid = blockIdx.x * 256 + threadIdx.x;
    const float QSCALE = 0.17677669529663687f * 1.4426950408889634f;
    if (tid < 24576) {                       // 384*256/4
        int o_lin = tid >> 6;
        int c4 = (tid & 63) * 4;
        int which = o_lin >> 7, r = o_lin & 127;
        int head = r >> 5, d = r & 31;
        int o_g = head * 96 + d * 3 + which;
        float4 v = *reinterpret_cast<const float4*>(wqkv + o_g * 256 + c4);
        float scl = (which == 0) ? QSCALE : 1.0f;
        uint2 pv;
        pv.x = packh2(v.x * scl, v.y * scl);
        pv.y = packh2(v.z * scl, v.w * scl);
        *reinterpret_cast<uint2*>(wqh + o_lin * 256 + c4) = pv;
    } else if (tid < 24576 + 8192) {         // 256*128/4
        int t2 = tid - 24576;
        float4 v = *reinterpret_cast<const float4*>(wout + t2 * 4);
        uint2 pv;
        pv.x = packh2(v.x, v.y);
        pv.y = packh2(v.z, v.w);
        *reinterpret_cast<uint2*>(woh + t2 * 4) = pv;
    }
}

// ---------------------------------------------------------------------------
// xpose: x[b][c][s] fp32 -> XT[b][s][c] f16 (64x64 LDS-transposed tiles)
// ---------------------------------------------------------------------------
__global__ __launch_bounds__(256) void xpose(const float* __restrict__ x,
                                             f16* __restrict__ xt) {
    __shared__ float T[64][65];
    const int s0 = blockIdx.x * 64, c0 = blockIdx.y * 64, b = blockIdx.z;
    const int t = threadIdx.x;
    #pragma unroll
    for (int i = 0; i < 16; ++i) {
        int e = t + i * 256;
        int c = e >> 6, s = e & 63;
        T[c][s] = x[((size_t)(b * NC + c0 + c)) * HW + s0 + s];
    }
    __syncthreads();
    const int s = t >> 2, cg = (t & 3) * 16;
    unsigned ov[8];
    #pragma unroll
    for (int i = 0; i < 8; ++i)
        ov[i] = packh2(T[cg + 2 * i][s], T[cg + 2 * i + 1][s]);
    f16* dst = xt + ((size_t)(b * HW + s0 + s)) * 256 + c0 + cg;
    *reinterpret_cast<uint4*>(dst)     = make_uint4(ov[0], ov[1], ov[2], ov[3]);
    *reinterpret_cast<uint4*>(dst + 8) = make_uint4(ov[4], ov[5], ov[6], ov[7]);
}

// ---------------------------------------------------------------------------
// qkv_mfma: C[s][o_lin] = XT * WQH^T  (f16 MFMA, K=256).
// VH2 layout: [bh][chunk=s/32][d32][s%32] (2KB per 32-key chunk), columns
// PERMUTED within the chunk so attn's post-QK lane-resident exp values are
// directly the PV B-fragment.  Chunk-tiling makes BOTH the V-write here and
// the V-read in attn fully coalesced (old [d][s4096] layout: 16 rows 8KB
// apart per access = 16x over-transaction, r10 diagnosis).
// ---------------------------------------------------------------------------
__global__ __launch_bounds__(256) void qkv_mfma(const f16* __restrict__ xt,
                                                const f16* __restrict__ wqh,
                                                f16* __restrict__ qt,
                                                f16* __restrict__ kt,
                                                f16* __restrict__ vh) {
    const int w = threadIdx.x >> 6, lane = threadIdx.x & 63;
    const int q15 = lane & 15, quad = lane >> 4;
    const int b = blockIdx.z;
    const int sTile = blockIdx.x * 64 + (w & 1) * 32;
    const int oTile = blockIdx.y * 64 + (w >> 1) * 32;
    const f16* A = xt + ((size_t)(b * HW + sTile)) * 256;

    f32x4 acc[2][2];
    #pragma unroll
    for (int i = 0; i < 2; ++i)
        #pragma unroll
        for (int j = 0; j < 2; ++j) acc[i][j] = (f32x4){0.f, 0.f, 0.f, 0.f};

    #pragma unroll
    for (int kc = 0; kc < 256; kc += 32) {
        f16x8 a0 = ldg_f16x8(A + (size_t)q15 * 256 + kc + quad * 8);
        f16x8 a1 = ldg_f16x8(A + (size_t)(16 + q15) * 256 + kc + quad * 8);
        f16x8 b0 = ldg_f16x8(wqh + (size_t)(oTile + q15) * 256 + kc + quad * 8);
        f16x8 b1 = ldg_f16x8(wqh + (size_t)(oTile + 16 + q15) * 256 + kc + quad * 8);
        acc[0][0] = __builtin_amdgcn_mfma_f32_16x16x32_f16(a0, b0, acc[0][0], 0, 0, 0);
        acc[0][1] = __builtin_amdgcn_mfma_f32_16x16x32_f16(a0, b1, acc[0][1], 0, 0, 0);
        acc[1][0] = __builtin_amdgcn_mfma_f32_16x16x32_f16(a1, b0, acc[1][0], 0, 0, 0);
        acc[1][1] = __builtin_amdgcn_mfma_f32_16x16x32_f16(a1, b1, acc[1][1], 0, 0, 0);
    }

    #pragma unroll
    for (int si = 0; si < 2; ++si)
        #pragma unroll
        for (int oj = 0; oj < 2; ++oj) {
            int o_lin = oTile + oj * 16 + q15;
            int which = o_lin >> 7;           // wave-uniform (tiles pure)
            int r = o_lin & 127;
            int head = r >> 5, d = r & 31;
            int bh = b * HEADS + head;
            int s2 = sTile + si * 16 + quad * 4;
            if (which == 2) {
                // keys s2..s2+3 (= si*16+quad*4+r2 within chunk sTile>>5) land
                // at within-chunk cols quad*8 + si*4 + r2 (permutation, r0)
                uint2 pv;
                pv.x = packh2(acc[si][oj][0], acc[si][oj][1]);
                pv.y = packh2(acc[si][oj][2], acc[si][oj][3]);
                f16* dst = vh + ((((size_t)bh * 128 + (sTile >> 5)) * 32 + d) << 5)
                              + quad * 8 + si * 4;
                *reinterpret_cast<uint2*>(dst) = pv;
            } else {
                f16* dst = (which == 0 ? qt : kt) + (size_t)bh * HW * 32;
                #pragma unroll
                for (int r2 = 0; r2 < 4; ++r2)
                    dst[(size_t)(s2 + r2) * 32 + d] = (f16)acc[si][oj][r2];
            }
        }
}

// ---------------------------------------------------------------------------
// attn_mfma: MFMA flash attention, no-max softmax, split-K over j (3 splits).
// Zero LDS; VH2 chunk-permutation makes exp values the PV B-fragment directly.
// r11 V-COALESCE: r10 diagnosis -- old VH [d][s4096] made each V load 16
// scattered 64B transactions (rows 8KB apart), ~34 txns/chunk vs K's ~2;
// transaction serialization was the invariant ~53us floor across r0-r10's
// scheduling variants.  VH2 [bh][chunk][d][32] makes each vf load ONE
// contiguous 1024B wave access.  Everything else identical to r10 (A/B
// 2-chunk sets, NSPLIT=3, 768 blocks=3/CU, runtime span -> rolled/low-VGPR).
// XCD-AFFINITY: 96 blocks/XCD = 3 (split,bh) combos x 32 q-blocks.
// NO launch_bounds min-occupancy arg (r2/r4: any hint -> spill storm).
// ---------------------------------------------------------------------------
#define MFMA16(A,B,C) __builtin_amdgcn_mfma_f32_16x16x32_f16(A,B,C,0,0,0)

#define LDKV(kd0,kd1,vd0,vd1,J)                                             \
    kd0 = ldg_f16x8(Kb + (size_t)((J) + q15) * 32 + quad * 8);              \
    kd1 = ldg_f16x8(Kb + (size_t)((J) + 16 + q15) * 32 + quad * 8);         \
    vd0 = ldg_f16x8(Vb + (((size_t)((J) >> 5) * 32 + q15) << 5) + quad * 8);\
    vd1 = ldg_f16x8(Vb + (((size_t)((J) >> 5) * 32 + 16 + q15) << 5) + quad * 8);

#define CHUNK(kf0_,kf1_,vf0_,vf1_)                                       \
    {                                                                    \
        const f32x4 z = {0.f, 0.f, 0.f, 0.f};                            \
        f32x4 s0a = MFMA16(kf0_, qf0, z);                                \
        f32x4 s1a = MFMA16(kf1_, qf0, z);                                \
        f32x4 s0b = MFMA16(kf0_, qf1, z);                                \
        f32x4 s1b = MFMA16(kf1_, qf1, z);                                \
        float ea[8], eb[8];                                              \
        _Pragma("unroll")                                                \
        for (int r = 0; r < 4; ++r) {                                    \
            ea[r]   = __builtin_amdgcn_exp2f(s0a[r]);                    \
            ea[4+r] = __builtin_amdgcn_exp2f(s1a[r]);                    \
            eb[r]   = __builtin_amdgcn_exp2f(s0b[r]);                    \
            eb[4+r] = __builtin_amdgcn_exp2f(s1b[r]);                    \
        }                                                                \
        l0 += (ea[0]+ea[1])+(ea[2]+ea[3])+(ea[4]+ea[5])+(ea[6]+ea[7]);   \
        l1 += (eb[0]+eb[1])+(eb[2]+eb[3])+(eb[4]+eb[5])+(eb[6]+eb[7]);   \
        union { unsigned u[4]; f16x8 v; } pa, pb;                        \
        pa.u[0] = packh2(ea[0], ea[1]); pa.u[1] = packh2(ea[2], ea[3]);  \
        pa.u[2] = packh2(ea[4], ea[5]); pa.u[3] = packh2(ea[6], ea[7]);  \
        pb.u[0] = packh2(eb[0], eb[1]); pb.u[1] = packh2(eb[2], eb[3]);  \
        pb.u[2] = packh2(eb[4], eb[5]); pb.u[3] = packh2(eb[6], eb[7]);  \
        acc[0][0] = MFMA16(vf0_, pa.v, acc[0][0]);                       \
        acc[0][1] = MFMA16(vf1_, pa.v, acc[0][1]);                       \
        acc[1][0] = MFMA16(vf0_, pb.v, acc[1][0]);                       \
        acc[1][1] = MFMA16(vf1_, pb.v, acc[1][1]);                       \
    }

__global__ __launch_bounds__(256) void attn_mfma(const f16* __restrict__ qt,
                                                 const f16* __restrict__ kt,
                                                 const f16* __restrict__ vh,
                                                 float* __restrict__ part) {
    const int w    = threadIdx.x >> 6;
    const int lane = threadIdx.x & 63;
    const int q15  = lane & 15;
    const int quad = lane >> 4;

    const int L    = blockIdx.x;          // 0..767
    const int xcd  = L & 7;               // dispatch round-robin -> XCD id
    const int slot = L >> 3;              // 0..95 within XCD
    const int combo = xcd * 3 + (slot >> 5);   // 0..23 = (split,bh)
    const int qblk  = slot & 31;
    const int bh    = combo & 7;
    const int split = combo >> 3;              // 0..2
    const int qbase = (qblk * 4 + w) * 32;

    const f16* Qb = qt + (size_t)bh * HW * 32;
    const f16* Kb = kt + (size_t)bh * HW * 32;
    const f16* Vb = vh + (size_t)bh * 128 * 1024;   // [chunk][d][32] tiles

    f16x8 qf0 = ldg_f16x8(Qb + (size_t)(qbase + q15) * 32 + quad * 8);
    f16x8 qf1 = ldg_f16x8(Qb + (size_t)(qbase + 16 + q15) * 32 + quad * 8);

    f32x4 acc[2][2];
    #pragma unroll
    for (int a = 0; a < 2; ++a)
        #pragma unroll
        for (int b2 = 0; b2 < 2; ++b2)
            acc[a][b2] = (f32x4){0.f, 0.f, 0.f, 0.f};
    float l0 = 0.f, l1 = 0.f;

    // splits: 22/21/21 double-chunks of 64 keys -> spans 1408/1344/1344
    const int j0   = split * 1344 + (split ? 64 : 0);
    const int span = 1344 + (split == 0 ? 64 : 0);

    f16x8 ka0, ka1, va0, va1, kb0, kb1, vb0, vb1;
    LDKV(ka0, ka1, va0, va1, j0);
    LDKV(kb0, kb1, vb0, vb1, j0 + 32);

    for (int jc = 0; jc < span; jc += 64) {
        CHUNK(ka0, ka1, va0, va1);
        LDKV(ka0, ka1, va0, va1, j0 + jc + 64);   // last-iter prefetch reads
        CHUNK(kb0, kb1, vb0, vb1);                // past span: valid ws mem,
        LDKV(kb0, kb1, vb0, vb1, j0 + jc + 96);   // values unused
    }

    float* P = part + (size_t)split * 33 * ROWS_TOTAL;
    #pragma unroll
    for (int qb = 0; qb < 2; ++qb) {
        float lv = qb ? l1 : l0;
        lv += __shfl_xor(lv, 16, 64);
        lv += __shfl_xor(lv, 32, 64);
        const int grow = bh * HW + qbase + qb * 16 + q15;
        if (quad == 0) P[grow] = lv;
        #pragma unroll
        for (int t = 0; t < 2; ++t)
            #pragma unroll
            for (int r = 0; r < 4; ++r) {
                int d = t * 16 + quad * 4 + r;
                P[(size_t)(1 + d) * ROWS_TOTAL + grow] = acc[qb][t][r];
            }
    }
}

// ---------------------------------------------------------------------------
// attn_merge: sum NSPLIT additive splits, normalize, write HIDT f16.
// thread = (grow, dquad): 131072 threads / 512 blocks, 27 independent 4B
// loads + one coalesced 16B write each (r7 fix: was 64us at 128 blocks).
// ---------------------------------------------------------------------------
__global__ __launch_bounds__(256) void attn_merge(const float* __restrict__ part,
                                                  f16* __restrict__ hidt) {
    const int t = blockIdx.x * 256 + threadIdx.x;      // 0..131071
    const int grow = t >> 2;                           // 0..32767
    const int dq   = t & 3;                            // 0..3 (8 d values each)
    float l = 0.f;
    #pragma unroll
    for (int sp = 0; sp < NSPLIT; ++sp)
        l += part[(size_t)sp * 33 * ROWS_TOTAL + grow];
    const float inv = 1.0f / l;
    const int bh = grow >> 12, s = grow & 4095;
    const int b = bh >> 2, h = bh & 3;

    unsigned ov[4];
    #pragma unroll
    for (int i = 0; i < 4; ++i) {
        const int d2 = dq * 4 + i;
        float o0 = 0.f, o1 = 0.f;
        #pragma unroll
        for (int sp = 0; sp < NSPLIT; ++sp) {
            const float* P = part + (size_t)sp * 33 * ROWS_TOTAL + grow;
            o0 += P[(size_t)(1 + 2 * d2) * ROWS_TOTAL];
            o1 += P[(size_t)(2 + 2 * d2) * ROWS_TOTAL];
        }
        ov[i] = packh2(o0 * inv, o1 * inv);
    }
    f16* dst = hidt + ((size_t)(b * HW + s)) * 128 + h * 32 + dq * 8;
    *reinterpret_cast<uint4*>(dst) = make_uint4(ov[0], ov[1], ov[2], ov[3]);
}

// ---------------------------------------------------------------------------
// outp_mfma: out[b][o][s] = HIDT * WOH^T + bias  (f16 MFMA, K=128, fp32 out)
// ---------------------------------------------------------------------------
__global__ __launch_bounds__(256) void outp_mfma(const f16* __restrict__ hidt,
                                                 const f16* __restrict__ woh,
                                                 const float* __restrict__ bout,
                                                 float* __restrict__ out) {
    const int w = threadIdx.x >> 6, lane = threadIdx.x & 63;
    const int q15 = lane & 15, quad = lane >> 4;
    const int b = blockIdx.z;
    const int sTile = blockIdx.x * 64 + (w & 1) * 32;
    const int oTile = blockIdx.y * 64 + (w >> 1) * 32;
    const f16* A = hidt + ((size_t)(b * HW + sTile)) * 128;

    f32x4 acc[2][2];
    #pragma unroll
    for (int i = 0; i < 2; ++i)
        #pragma unroll
        for (int j = 0; j < 2; ++j) acc[i][j] = (f32x4){0.f, 0.f, 0.f, 0.f};

    #pragma unroll
    for (int kc = 0; kc < 128; kc += 32) {
        f16x8 a0 = ldg_f16x8(A + (size_t)q15 * 128 + kc + quad * 8);
        f16x8 a1 = ldg_f16x8(A + (size_t)(16 + q15) * 128 + kc + quad * 8);
        f16x8 b0 = ldg_f16x8(woh + (size_t)(oTile + q15) * 128 + kc + quad * 8);
        f16x8 b1 = ldg_f16x8(woh + (size_t)(oTile + 16 + q15) * 128 + kc + quad * 8);
        acc[0][0] = __builtin_amdgcn_mfma_f32_16x16x32_f16(a0, b0, acc[0][0], 0, 0, 0);
        acc[0][1] = __builtin_amdgcn_mfma_f32_16x16x32_f16(a0, b1, acc[0][1], 0, 0, 0);
        acc[1][0] = __builtin_amdgcn_mfma_f32_16x16x32_f16(a1, b0, acc[1][0], 0, 0, 0);
        acc[1][1] = __builtin_amdgcn_mfma_f32_16x16x32_f16(a1, b1, acc[1][1], 0, 0, 0);
    }

    #pragma unroll
    for (int oj = 0; oj < 2; ++oj) {
        const int o = oTile + oj * 16 + q15;
        const float bias = bout[o];
        #pragma unroll
        for (int si = 0; si < 2; ++si) {
            const int s2 = sTile + si * 16 + quad * 4;
            float4 v = make_float4(acc[si][oj][0] + bias, acc[si][oj][1] + bias,
                                   acc[si][oj][2] + bias, acc[si][oj][3] + bias);
            *reinterpret_cast<float4*>(out + ((size_t)(b * NC + o)) * HW + s2) = v;
        }
    }
}

// ---------------------------------------------------------------------------
extern "C" void kernel_launch(void* const* d_in, const int* in_sizes, int n_in,
                              void* d_out, int out_size, void* d_ws, size_t ws_size,
                              hipStream_t stream) {
    const float* x    = (const float*)d_in[0];
    const float* wqkv = (const float*)d_in[1];
    const float* wout = (const float*)d_in[2];
    const float* bout = (const float*)d_in[3];
    float* out = (float*)d_out;
    char* wsb  = (char*)d_ws;

    f16*   XT   = (f16*)(wsb + XT_OFF);
    f16*   QT   = (f16*)(wsb + QT_OFF);
    f16*   KT   = (f16*)(wsb + KT_OFF);
    f16*   VH   = (f16*)(wsb + VH_OFF);
    f16*   HIDT = (f16*)(wsb + HIDT_OFF);
    f16*   WQH  = (f16*)(wsb + WQH_OFF);
    f16*   WOH  = (f16*)(wsb + WOH_OFF);
    float* PART = (float*)(wsb + PART_OFF);

    wconv    <<<dim3(128), 256, 0, stream>>>(wqkv, wout, WQH, WOH);
    xpose    <<<dim3(64, 4, NB), 256, 0, stream>>>(x, XT);
    qkv_mfma <<<dim3(64, 6, NB), 256, 0, stream>>>(XT, WQH, QT, KT, VH);
    attn_mfma<<<dim3(768), 256, 0, stream>>>(QT, KT, VH, PART);
    attn_merge<<<dim3(512), 256, 0, stream>>>(PART, HIDT);
    outp_mfma<<<dim3(64, 4, NB), 256, 0, stream>>>(HIDT, WOH, bout, out);
}

// Round 12
// 122.712 us; speedup vs baseline: 1.2770x; 1.0462x over previous
//
#include <hip/hip_runtime.h>

#define HEADS 4
#define DIM_HEAD 32
#define NB 2
#define NC 256
#define HW 4096
#define HIDDEN 128
#define NBH (NB*HEADS)
#define ROWS_TOTAL (NBH*HW)   // 32768

typedef _Float16 f16;
typedef _Float16 f16x8 __attribute__((ext_vector_type(8)));
typedef __fp16 fp16x2 __attribute__((ext_vector_type(2)));
typedef float f32x4 __attribute__((ext_vector_type(4)));

// workspace layout (bytes).  ALL mfma operand arrays are FRAGMENT-TILED:
// [row/16][k/32][16][32] f16 (1KB tiles) so every A/B fragment load
// (base + q15*32 + quad*8) is ONE contiguous 1KB wave access -- the r11
// mechanism (V chunk-tiling, attn 53.7->~39us) applied to qkv/outp.
#define XT_OFF   0u                       // f16 [b][s/16][c/32=8][16][32]   4 MB
#define QT_OFF   (4u<<20)                 // f16 [bh][s][d32]     2 MB (rowstride 32 = already coalesced)
#define KT_OFF   (6u<<20)                 // f16 [bh][s][d32]     2 MB
#define VH_OFF   (8u<<20)                 // f16 [bh][s/32][d32][32]  2 MB  (chunk-tiled, cols permuted)
#define HIDT_OFF (10u<<20)                // f16 [b][s/16][c/32=4][16][32]   2 MB
#define WQH_OFF  (12u<<20)                // f16 [384/16][256/32=8][16][32]  192 KB
#define WOH_OFF  ((12u<<20) + (256u<<10)) // f16 [256/16][128/32=4][16][32]  64 KB
#define PART_OFF (13u<<20)                // f32 [split][33][32768]  13 MB (3 splits)
#define NSPLIT 3                          // 768 blocks = 3/CU: ONE generation
                                          // (r8-proven; r9 showed 6/CU regresses)

__device__ __forceinline__ f16x8 ldg_f16x8(const f16* p) {
    union { uint4 u; f16x8 v; } t;
    t.u = *reinterpret_cast<const uint4*>(p);
    return t.v;
}
__device__ __forceinline__ unsigned packh2(float a, float b) {
    union { fp16x2 h; unsigned u; } t;
    t.h = __builtin_amdgcn_cvt_pkrtz(a, b);
    return t.u;
}

// ---------------------------------------------------------------------------
// wconv: permute+convert weights to f16, writing TILED layouts.
// ---------------------------------------------------------------------------
__global__ __launch_bounds__(256) void wconv(const float* __restrict__ wqkv,
                                             const float* __restrict__ wout,
                                             f16* __restrict__ wqh,
                                             f16* __restrict__ woh) {
    const int tid = blockIdx.x * 256 + threadIdx.x;
    const float QSCALE = 0.17677669529663687f * 1.4426950408889634f;
    if (tid < 24576) {                       // 384*256/4
        int o_lin = tid >> 6;
        int c4 = (tid & 63) * 4;
        int which = o_lin >> 7, r = o_lin & 127;
        int head = r >> 5, d = r & 31;
        int o_g = head * 96 + d * 3 + which;
        float4 v = *reinterpret_cast<const float4*>(wqkv + o_g * 256 + c4);
        float scl = (which == 0) ? QSCALE : 1.0f;
        uint2 pv;
        pv.x = packh2(v.x * scl, v.y * scl);
        pv.y = packh2(v.z * scl, v.w * scl);
        f16* dst = wqh + (((o_lin >> 4) * 8 + (c4 >> 5)) << 9)
                       + (o_lin & 15) * 32 + (c4 & 31);
        *reinterpret_cast<uint2*>(dst) = pv;
    } else if (tid < 24576 + 8192) {         // 256*128/4
        int t2 = tid - 24576;
        int o = t2 >> 5;                     // row in [0,256)
        int c4 = (t2 * 4) & 127;             // col in [0,128)
        float4 v = *reinterpret_cast<const float4*>(wout + t2 * 4);
        uint2 pv;
        pv.x = packh2(v.x, v.y);
        pv.y = packh2(v.z, v.w);
        f16* dst = woh + (((o >> 4) * 4 + (c4 >> 5)) << 9)
                       + (o & 15) * 32 + (c4 & 31);
        *reinterpret_cast<uint2*>(dst) = pv;
    }
}

// ---------------------------------------------------------------------------
// xpose: x[b][c][s] fp32 -> XT tiled [b][s/16][c/32][16][32] f16
// ---------------------------------------------------------------------------
__global__ __launch_bounds__(256) void xpose(const float* __restrict__ x,
                                             f16* __restrict__ xt) {
    __shared__ float T[64][65];
    const int s0 = blockIdx.x * 64, c0 = blockIdx.y * 64, b = blockIdx.z;
    const int t = threadIdx.x;
    #pragma unroll
    for (int i = 0; i < 16; ++i) {
        int e = t + i * 256;
        int c = e >> 6, s = e & 63;
        T[c][s] = x[((size_t)(b * NC + c0 + c)) * HW + s0 + s];
    }
    __syncthreads();
    const int s = t >> 2, cg = (t & 3) * 16;
    unsigned ov[8];
    #pragma unroll
    for (int i = 0; i < 8; ++i)
        ov[i] = packh2(T[cg + 2 * i][s], T[cg + 2 * i + 1][s]);
    const int srow = s0 + s;
    f16* dst = xt + ((((size_t)(b * 256 + (srow >> 4))) * 8 + ((c0 + cg) >> 5)) << 9)
                  + (srow & 15) * 32 + (cg & 31);
    *reinterpret_cast<uint4*>(dst)     = make_uint4(ov[0], ov[1], ov[2], ov[3]);
    *reinterpret_cast<uint4*>(dst + 8) = make_uint4(ov[4], ov[5], ov[6], ov[7]);
}

// ---------------------------------------------------------------------------
// qkv_mfma: C[s][o_lin] = XT * WQH^T  (f16 MFMA, K=256).  XT/WQH tiled ->
// every fragment load is one contiguous 1KB wave access (was 16x64B scatter).
// VH chunk-tiled [bh][s/32][d][32] with per-chunk column permutation (r0/r11).
// ---------------------------------------------------------------------------
__global__ __launch_bounds__(256) void qkv_mfma(const f16* __restrict__ xt,
                                                const f16* __restrict__ wqh,
                                                f16* __restrict__ qt,
                                                f16* __restrict__ kt,
                                                f16* __restrict__ vh) {
    const int w = threadIdx.x >> 6, lane = threadIdx.x & 63;
    const int q15 = lane & 15, quad = lane >> 4;
    const int b = blockIdx.z;
    const int sTile = blockIdx.x * 64 + (w & 1) * 32;
    const int oTile = blockIdx.y * 64 + (w >> 1) * 32;
    const f16* At = xt + (((size_t)(b * 256 + (sTile >> 4))) << 12);  // *8 tiles *512
    const f16* Bt = wqh + (((size_t)(oTile >> 4)) << 12);
    const int fo = q15 * 32 + quad * 8;

    f32x4 acc[2][2];
    #pragma unroll
    for (int i = 0; i < 2; ++i)
        #pragma unroll
        for (int j = 0; j < 2; ++j) acc[i][j] = (f32x4){0.f, 0.f, 0.f, 0.f};

    #pragma unroll
    for (int kc = 0; kc < 256; kc += 32) {
        const int kt5 = (kc >> 5) << 9;
        f16x8 a0 = ldg_f16x8(At + kt5 + fo);
        f16x8 a1 = ldg_f16x8(At + 4096 + kt5 + fo);
        f16x8 b0 = ldg_f16x8(Bt + kt5 + fo);
        f16x8 b1 = ldg_f16x8(Bt + 4096 + kt5 + fo);
        acc[0][0] = __builtin_amdgcn_mfma_f32_16x16x32_f16(a0, b0, acc[0][0], 0, 0, 0);
        acc[0][1] = __builtin_amdgcn_mfma_f32_16x16x32_f16(a0, b1, acc[0][1], 0, 0, 0);
        acc[1][0] = __builtin_amdgcn_mfma_f32_16x16x32_f16(a1, b0, acc[1][0], 0, 0, 0);
        acc[1][1] = __builtin_amdgcn_mfma_f32_16x16x32_f16(a1, b1, acc[1][1], 0, 0, 0);
    }

    #pragma unroll
    for (int si = 0; si < 2; ++si)
        #pragma unroll
        for (int oj = 0; oj < 2; ++oj) {
            int o_lin = oTile + oj * 16 + q15;
            int which = o_lin >> 7;           // wave-uniform (tiles pure)
            int r = o_lin & 127;
            int head = r >> 5, d = r & 31;
            int bh = b * HEADS + head;
            int s2 = sTile + si * 16 + quad * 4;
            if (which == 2) {
                // keys s2..s2+3 (= si*16+quad*4+r2 within chunk sTile>>5) land
                // at within-chunk cols quad*8 + si*4 + r2 (permutation, r0)
                uint2 pv;
                pv.x = packh2(acc[si][oj][0], acc[si][oj][1]);
                pv.y = packh2(acc[si][oj][2], acc[si][oj][3]);
                f16* dst = vh + ((((size_t)bh * 128 + (sTile >> 5)) * 32 + d) << 5)
                              + quad * 8 + si * 4;
                *reinterpret_cast<uint2*>(dst) = pv;
            } else {
                f16* dst = (which == 0 ? qt : kt) + (size_t)bh * HW * 32;
                #pragma unroll
                for (int r2 = 0; r2 < 4; ++r2)
                    dst[(size_t)(s2 + r2) * 32 + d] = (f16)acc[si][oj][r2];
            }
        }
}

// ---------------------------------------------------------------------------
// attn_mfma: MFMA flash attention, no-max softmax, split-K over j (3 splits).
// UNCHANGED from r11 (proven ~39us): zero LDS, VH chunk-tiled+permuted so
// exp values feed PV directly; all K/Q/V loads 1KB-coalesced; A/B 2-chunk
// register sets; NSPLIT=3 -> 768 blocks = 3/CU one generation; runtime span
// keeps the rolled low-VGPR form (VGPR ~56).
// XCD-AFFINITY: 96 blocks/XCD = 3 (split,bh) combos x 32 q-blocks.
// NO launch_bounds min-occupancy arg (r2/r4: any hint -> spill storm).
// ---------------------------------------------------------------------------
#define MFMA16(A,B,C) __builtin_amdgcn_mfma_f32_16x16x32_f16(A,B,C,0,0,0)

#define LDKV(kd0,kd1,vd0,vd1,J)                                             \
    kd0 = ldg_f16x8(Kb + (size_t)((J) + q15) * 32 + quad * 8);              \
    kd1 = ldg_f16x8(Kb + (size_t)((J) + 16 + q15) * 32 + quad * 8);         \
    vd0 = ldg_f16x8(Vb + (((size_t)((J) >> 5) * 32 + q15) << 5) + quad * 8);\
    vd1 = ldg_f16x8(Vb + (((size_t)((J) >> 5) * 32 + 16 + q15) << 5) + quad * 8);

#define CHUNK(kf0_,kf1_,vf0_,vf1_)                                       \
    {                                                                    \
        const f32x4 z = {0.f, 0.f, 0.f, 0.f};                            \
        f32x4 s0a = MFMA16(kf0_, qf0, z);                                \
        f32x4 s1a = MFMA16(kf1_, qf0, z);                                \
        f32x4 s0b = MFMA16(kf0_, qf1, z);                                \
        f32x4 s1b = MFMA16(kf1_, qf1, z);                                \
        float ea[8], eb[8];                                              \
        _Pragma("unroll")                                                \
        for (int r = 0; r < 4; ++r) {                                    \
            ea[r]   = __builtin_amdgcn_exp2f(s0a[r]);                    \
            ea[4+r] = __builtin_amdgcn_exp2f(s1a[r]);                    \
            eb[r]   = __builtin_amdgcn_exp2f(s0b[r]);                    \
            eb[4+r] = __builtin_amdgcn_exp2f(s1b[r]);                    \
        }                                                                \
        l0 += (ea[0]+ea[1])+(ea[2]+ea[3])+(ea[4]+ea[5])+(ea[6]+ea[7]);   \
        l1 += (eb[0]+eb[1])+(eb[2]+eb[3])+(eb[4]+eb[5])+(eb[6]+eb[7]);   \
        union { unsigned u[4]; f16x8 v; } pa, pb;                        \
        pa.u[0] = packh2(ea[0], ea[1]); pa.u[1] = packh2(ea[2], ea[3]);  \
        pa.u[2] = packh2(ea[4], ea[5]); pa.u[3] = packh2(ea[6], ea[7]);  \
        pb.u[0] = packh2(eb[0], eb[1]); pb.u[1] = packh2(eb[2], eb[3]);  \
        pb.u[2] = packh2(eb[4], eb[5]); pb.u[3] = packh2(eb[6], eb[7]);  \
        acc[0][0] = MFMA16(vf0_, pa.v, acc[0][0]);                       \
        acc[0][1] = MFMA16(vf1_, pa.v, acc[0][1]);                       \
        acc[1][0] = MFMA16(vf0_, pb.v, acc[1][0]);                       \
        acc[1][1] = MFMA16(vf1_, pb.v, acc[1][1]);                       \
    }

__global__ __launch_bounds__(256) void attn_mfma(const f16* __restrict__ qt,
                                                 const f16* __restrict__ kt,
                                                 const f16* __restrict__ vh,
                                                 float* __restrict__ part) {
    const int w    = threadIdx.x >> 6;
    const int lane = threadIdx.x & 63;
    const int q15  = lane & 15;
    const int quad = lane >> 4;

    const int L    = blockIdx.x;          // 0..767
    const int xcd  = L & 7;               // dispatch round-robin -> XCD id
    const int slot = L >> 3;              // 0..95 within XCD
    const int combo = xcd * 3 + (slot >> 5);   // 0..23 = (split,bh)
    const int qblk  = slot & 31;
    const int bh    = combo & 7;
    const int split = combo >> 3;              // 0..2
    const int qbase = (qblk * 4 + w) * 32;

    const f16* Qb = qt + (size_t)bh * HW * 32;
    const f16* Kb = kt + (size_t)bh * HW * 32;
    const f16* Vb = vh + (size_t)bh * 128 * 1024;   // [chunk][d][32] tiles

    f16x8 qf0 = ldg_f16x8(Qb + (size_t)(qbase + q15) * 32 + quad * 8);
    f16x8 qf1 = ldg_f16x8(Qb + (size_t)(qbase + 16 + q15) * 32 + quad * 8);

    f32x4 acc[2][2];
    #pragma unroll
    for (int a = 0; a < 2; ++a)
        #pragma unroll
        for (int b2 = 0; b2 < 2; ++b2)
            acc[a][b2] = (f32x4){0.f, 0.f, 0.f, 0.f};
    float l0 = 0.f, l1 = 0.f;

    // splits: 22/21/21 double-chunks of 64 keys -> spans 1408/1344/1344
    const int j0   = split * 1344 + (split ? 64 : 0);
    const int span = 1344 + (split == 0 ? 64 : 0);

    f16x8 ka0, ka1, va0, va1, kb0, kb1, vb0, vb1;
    LDKV(ka0, ka1, va0, va1, j0);
    LDKV(kb0, kb1, vb0, vb1, j0 + 32);

    for (int jc = 0; jc < span; jc += 64) {
        CHUNK(ka0, ka1, va0, va1);
        LDKV(ka0, ka1, va0, va1, j0 + jc + 64);   // last-iter prefetch reads
        CHUNK(kb0, kb1, vb0, vb1);                // past span: valid ws mem,
        LDKV(kb0, kb1, vb0, vb1, j0 + jc + 96);   // values unused
    }

    float* P = part + (size_t)split * 33 * ROWS_TOTAL;
    #pragma unroll
    for (int qb = 0; qb < 2; ++qb) {
        float lv = qb ? l1 : l0;
        lv += __shfl_xor(lv, 16, 64);
        lv += __shfl_xor(lv, 32, 64);
        const int grow = bh * HW + qbase + qb * 16 + q15;
        if (quad == 0) P[grow] = lv;
        #pragma unroll
        for (int t = 0; t < 2; ++t)
            #pragma unroll
            for (int r = 0; r < 4; ++r) {
                int d = t * 16 + quad * 4 + r;
                P[(size_t)(1 + d) * ROWS_TOTAL + grow] = acc[qb][t][r];
            }
    }
}

// ---------------------------------------------------------------------------
// attn_merge: sum NSPLIT additive splits, normalize, write HIDT (tiled).
// r12 lane order: grow = blk*64 + (t&63), dq = t>>6 -> every PART load is
// 64 consecutive grows = fully coalesced 256B (old order: 16 distinct words
// per wave load, 4x dup).  27 loads + one 16B write per thread.
// ---------------------------------------------------------------------------
__global__ __launch_bounds__(256) void attn_merge(const float* __restrict__ part,
                                                  f16* __restrict__ hidt) {
    const int grow = blockIdx.x * 64 + (threadIdx.x & 63);   // 0..32767
    const int dq   = threadIdx.x >> 6;                       // 0..3
    float l = 0.f;
    #pragma unroll
    for (int sp = 0; sp < NSPLIT; ++sp)
        l += part[(size_t)sp * 33 * ROWS_TOTAL + grow];
    const float inv = 1.0f / l;
    const int bh = grow >> 12, s = grow & 4095;
    const int b = bh >> 2, h = bh & 3;

    unsigned ov[4];
    #pragma unroll
    for (int i = 0; i < 4; ++i) {
        const int d2 = dq * 4 + i;
        float o0 = 0.f, o1 = 0.f;
        #pragma unroll
        for (int sp = 0; sp < NSPLIT; ++sp) {
            const float* P = part + (size_t)sp * 33 * ROWS_TOTAL + grow;
            o0 += P[(size_t)(1 + 2 * d2) * ROWS_TOTAL];
            o1 += P[(size_t)(2 + 2 * d2) * ROWS_TOTAL];
        }
        ov[i] = packh2(o0 * inv, o1 * inv);
    }
    // HIDT tiled [b][s/16][4][16][32]: c = h*32 + dq*8 -> k_tile = h
    f16* dst = hidt + ((((size_t)(b * 256 + (s >> 4))) * 4 + h) << 9)
                    + (s & 15) * 32 + dq * 8;
    *reinterpret_cast<uint4*>(dst) = make_uint4(ov[0], ov[1], ov[2], ov[3]);
}

// ---------------------------------------------------------------------------
// outp_mfma: out[b][o][s] = HIDT * WOH^T + bias  (f16 MFMA, K=128, fp32 out)
// HIDT/WOH tiled -> fragment loads are contiguous 1KB wave accesses.
// ---------------------------------------------------------------------------
__global__ __launch_bounds__(256) void outp_mfma(const f16* __restrict__ hidt,
                                                 const f16* __restrict__ woh,
                                                 const float* __restrict__ bout,
                                                 float* __restrict__ out) {
    const int w = threadIdx.x >> 6, lane = threadIdx.x & 63;
    const int q15 = lane & 15, quad = lane >> 4;
    const int b = blockIdx.z;
    const int sTile = blockIdx.x * 64 + (w & 1) * 32;
    const int oTile = blockIdx.y * 64 + (w >> 1) * 32;
    const f16* At = hidt + (((size_t)(b * 256 + (sTile >> 4))) << 11);  // *4 tiles *512
    const f16* Bt = woh + (((size_t)(oTile >> 4)) << 11);
    const int fo = q15 * 32 + quad * 8;

    f32x4 acc[2][2];
    #pragma unroll
    for (int i = 0; i < 2; ++i)
        #pragma unroll
        for (int j = 0; j < 2; ++j) acc[i][j] = (f32x4){0.f, 0.f, 0.f, 0.f};

    #pragma unroll
    for (int kc = 0; kc < 128; kc += 32) {
        const int kt5 = (kc >> 5) << 9;
        f16x8 a0 = ldg_f16x8(At + kt5 + fo);
        f16x8 a1 = ldg_f16x8(At + 2048 + kt5 + fo);
        f16x8 b0 = ldg_f16x8(Bt + kt5 + fo);
        f16x8 b1 = ldg_f16x8(Bt + 2048 + kt5 + fo);
        acc[0][0] = __builtin_amdgcn_mfma_f32_16x16x32_f16(a0, b0, acc[0][0], 0, 0, 0);
        acc[0][1] = __builtin_amdgcn_mfma_f32_16x16x32_f16(a0, b1, acc[0][1], 0, 0, 0);
        acc[1][0] = __builtin_amdgcn_mfma_f32_16x16x32_f16(a1, b0, acc[1][0], 0, 0, 0);
        acc[1][1] = __builtin_amdgcn_mfma_f32_16x16x32_f16(a1, b1, acc[1][1], 0, 0, 0);
    }

    #pragma unroll
    for (int oj = 0; oj < 2; ++oj) {
        const int o = oTile + oj * 16 + q15;
        const float bias = bout[o];
        #pragma unroll
        for (int si = 0; si < 2; ++si) {
            const int s2 = sTile + si * 16 + quad * 4;
            float4 v = make_float4(acc[si][oj][0] + bias, acc[si][oj][1] + bias,
                                   acc[si][oj][2] + bias, acc[si][oj][3] + bias);
            *reinterpret_cast<float4*>(out + ((size_t)(b * NC + o)) * HW + s2) = v;
        }
    }
}

// ---------------------------------------------------------------------------
extern "C" void kernel_launch(void* const* d_in, const int* in_sizes, int n_in,
                              void* d_out, int out_size, void* d_ws, size_t ws_size,
                              hipStream_t stream) {
    const float* x    = (const float*)d_in[0];
    const float* wqkv = (const float*)d_in[1];
    const float* wout = (const float*)d_in[2];
    const float* bout = (const float*)d_in[3];
    float* out = (float*)d_out;
    char* wsb  = (char*)d_ws;

    f16*   XT   = (f16*)(wsb + XT_OFF);
    f16*   QT   = (f16*)(wsb + QT_OFF);
    f16*   KT   = (f16*)(wsb + KT_OFF);
    f16*   VH   = (f16*)(wsb + VH_OFF);
    f16*   HIDT = (f16*)(wsb + HIDT_OFF);
    f16*   WQH  = (f16*)(wsb + WQH_OFF);
    f16*   WOH  = (f16*)(wsb + WOH_OFF);
    float* PART = (float*)(wsb + PART_OFF);

    wconv    <<<dim3(128), 256, 0, stream>>>(wqkv, wout, WQH, WOH);
    xpose    <<<dim3(64, 4, NB), 256, 0, stream>>>(x, XT);
    qkv_mfma <<<dim3(64, 6, NB), 256, 0, stream>>>(XT, WQH, QT, KT, VH);
    attn_mfma<<<dim3(768), 256, 0, stream>>>(QT, KT, VH, PART);
    attn_merge<<<dim3(512), 256, 0, stream>>>(PART, HIDT);
    outp_mfma<<<dim3(64, 4, NB), 256, 0, stream>>>(HIDT, WOH, bout, out);
}

// Round 13
// 122.073 us; speedup vs baseline: 1.2837x; 1.0052x over previous
//
#include <hip/hip_runtime.h>

#define HEADS 4
#define DIM_HEAD 32
#define NB 2
#define NC 256
#define HW 4096
#define HIDDEN 128
#define NBH (NB*HEADS)
#define ROWS_TOTAL (NBH*HW)   // 32768

typedef _Float16 f16;
typedef _Float16 f16x8 __attribute__((ext_vector_type(8)));
typedef __fp16 fp16x2 __attribute__((ext_vector_type(2)));
typedef float f32x4 __attribute__((ext_vector_type(4)));

// workspace layout (bytes).  ALL mfma operand arrays are FRAGMENT-TILED:
// [row/16][k/32][16][32] f16 (1KB tiles) so every A/B fragment load
// (base + q15*32 + quad*8) is ONE contiguous 1KB wave access (r11/r12
// mechanism: attn 53.7->41.6, qkv/outp -5.7us total).
#define XT_OFF   0u                       // f16 [b][s/16][c/32=8][16][32]   4 MB
#define QT_OFF   (4u<<20)                 // f16 [bh][s][d32]     2 MB (rowstride 32 = coalesced)
#define KT_OFF   (6u<<20)                 // f16 [bh][s][d32]     2 MB
#define VH_OFF   (8u<<20)                 // f16 [bh][s/32][d32][32]  2 MB  (chunk-tiled, cols permuted)
#define HIDT_OFF (10u<<20)                // f16 [b][s/16][c/32=4][16][32]   2 MB
#define WQH_OFF  (12u<<20)                // f16 [384/16][256/32=8][16][32]  192 KB
#define WOH_OFF  ((12u<<20) + (256u<<10)) // f16 [256/16][128/32=4][16][32]  64 KB
#define PART_OFF (13u<<20)                // f32 [split][33][32768]  17.3 MB (4 splits)
#define NSPLIT 4                          // 1024 blocks = 4/CU: ONE generation.
                                          // r9's "more waves regress" was measured
                                          // with 16x-uncoalesced V (confound removed
                                          // r11); retest wave count at 4/SIMD.

__device__ __forceinline__ f16x8 ldg_f16x8(const f16* p) {
    union { uint4 u; f16x8 v; } t;
    t.u = *reinterpret_cast<const uint4*>(p);
    return t.v;
}
__device__ __forceinline__ unsigned packh2(float a, float b) {
    union { fp16x2 h; unsigned u; } t;
    t.h = __builtin_amdgcn_cvt_pkrtz(a, b);
    return t.u;
}

// ---------------------------------------------------------------------------
// prep: FUSED wconv + xpose (independent preprocessing, block-partitioned)
// -- deletes one kernel-drain boundary from the 6-deep serial chain.
// blocks 0..511: xpose  x[b][c][s] fp32 -> XT tiled [b][s/16][c/32][16][32]
// blocks 512..639: wconv -> WQH/WOH tiled
// ---------------------------------------------------------------------------
__global__ __launch_bounds__(256) void prep(const float* __restrict__ x,
                                            const float* __restrict__ wqkv,
                                            const float* __restrict__ wout,
                                            f16* __restrict__ xt,
                                            f16* __restrict__ wqh,
                                            f16* __restrict__ woh) {
    __shared__ float T[64][65];
    if (blockIdx.x < 512) {
        const int idx = blockIdx.x;
        const int b = idx >> 8, rem = idx & 255;
        const int c0 = (rem >> 6) * 64, s0 = (rem & 63) * 64;
        const int t = threadIdx.x;
        #pragma unroll
        for (int i = 0; i < 16; ++i) {
            int e = t + i * 256;
            int c = e >> 6, s = e & 63;
            T[c][s] = x[((size_t)(b * NC + c0 + c)) * HW + s0 + s];
        }
        __syncthreads();
        const int s = t >> 2, cg = (t & 3) * 16;
        unsigned ov[8];
        #pragma unroll
        for (int i = 0; i < 8; ++i)
            ov[i] = packh2(T[cg + 2 * i][s], T[cg + 2 * i + 1][s]);
        const int srow = s0 + s;
        f16* dst = xt + ((((size_t)(b * 256 + (srow >> 4))) * 8 + ((c0 + cg) >> 5)) << 9)
                      + (srow & 15) * 32 + (cg & 31);
        *reinterpret_cast<uint4*>(dst)     = make_uint4(ov[0], ov[1], ov[2], ov[3]);
        *reinterpret_cast<uint4*>(dst + 8) = make_uint4(ov[4], ov[5], ov[6], ov[7]);
        return;
    }
    const int tid = (blockIdx.x - 512) * 256 + threadIdx.x;
    const float QSCALE = 0.17677669529663687f * 1.4426950408889634f;
    if (tid < 24576) {                       // 384*256/4
        int o_lin = tid >> 6;
        int c4 = (tid & 63) * 4;
        int which = o_lin >> 7, r = o_lin & 127;
        int head = r >> 5, d = r & 31;
        int o_g = head * 96 + d * 3 + which;
        float4 v = *reinterpret_cast<const float4*>(wqkv + o_g * 256 + c4);
        float scl = (which == 0) ? QSCALE : 1.0f;
        uint2 pv;
        pv.x = packh2(v.x * scl, v.y * scl);
        pv.y = packh2(v.z * scl, v.w * scl);
        f16* dst = wqh + (((o_lin >> 4) * 8 + (c4 >> 5)) << 9)
                       + (o_lin & 15) * 32 + (c4 & 31);
        *reinterpret_cast<uint2*>(dst) = pv;
    } else if (tid < 24576 + 8192) {         // 256*128/4
        int t2 = tid - 24576;
        int o = t2 >> 5;                     // row in [0,256)
        int c4 = (t2 * 4) & 127;             // col in [0,128)
        float4 v = *reinterpret_cast<const float4*>(wout + t2 * 4);
        uint2 pv;
        pv.x = packh2(v.x, v.y);
        pv.y = packh2(v.z, v.w);
        f16* dst = woh + (((o >> 4) * 4 + (c4 >> 5)) << 9)
                       + (o & 15) * 32 + (c4 & 31);
        *reinterpret_cast<uint2*>(dst) = pv;
    }
}

// ---------------------------------------------------------------------------
// qkv_mfma: C[s][o_lin] = XT * WQH^T  (f16 MFMA, K=256).  XT/WQH tiled ->
// every fragment load is one contiguous 1KB wave access.
// VH chunk-tiled [bh][s/32][d][32] with per-chunk column permutation (r0/r11).
// ---------------------------------------------------------------------------
__global__ __launch_bounds__(256) void qkv_mfma(const f16* __restrict__ xt,
                                                const f16* __restrict__ wqh,
                                                f16* __restrict__ qt,
                                                f16* __restrict__ kt,
                                                f16* __restrict__ vh) {
    const int w = threadIdx.x >> 6, lane = threadIdx.x & 63;
    const int q15 = lane & 15, quad = lane >> 4;
    const int b = blockIdx.z;
    const int sTile = blockIdx.x * 64 + (w & 1) * 32;
    const int oTile = blockIdx.y * 64 + (w >> 1) * 32;
    const f16* At = xt + (((size_t)(b * 256 + (sTile >> 4))) << 12);  // *8 tiles *512
    const f16* Bt = wqh + (((size_t)(oTile >> 4)) << 12);
    const int fo = q15 * 32 + quad * 8;

    f32x4 acc[2][2];
    #pragma unroll
    for (int i = 0; i < 2; ++i)
        #pragma unroll
        for (int j = 0; j < 2; ++j) acc[i][j] = (f32x4){0.f, 0.f, 0.f, 0.f};

    #pragma unroll
    for (int kc = 0; kc < 256; kc += 32) {
        const int kt5 = (kc >> 5) << 9;
        f16x8 a0 = ldg_f16x8(At + kt5 + fo);
        f16x8 a1 = ldg_f16x8(At + 4096 + kt5 + fo);
        f16x8 b0 = ldg_f16x8(Bt + kt5 + fo);
        f16x8 b1 = ldg_f16x8(Bt + 4096 + kt5 + fo);
        acc[0][0] = __builtin_amdgcn_mfma_f32_16x16x32_f16(a0, b0, acc[0][0], 0, 0, 0);
        acc[0][1] = __builtin_amdgcn_mfma_f32_16x16x32_f16(a0, b1, acc[0][1], 0, 0, 0);
        acc[1][0] = __builtin_amdgcn_mfma_f32_16x16x32_f16(a1, b0, acc[1][0], 0, 0, 0);
        acc[1][1] = __builtin_amdgcn_mfma_f32_16x16x32_f16(a1, b1, acc[1][1], 0, 0, 0);
    }

    #pragma unroll
    for (int si = 0; si < 2; ++si)
        #pragma unroll
        for (int oj = 0; oj < 2; ++oj) {
            int o_lin = oTile + oj * 16 + q15;
            int which = o_lin >> 7;           // wave-uniform (tiles pure)
            int r = o_lin & 127;
            int head = r >> 5, d = r & 31;
            int bh = b * HEADS + head;
            int s2 = sTile + si * 16 + quad * 4;
            if (which == 2) {
                // keys s2..s2+3 (= si*16+quad*4+r2 within chunk sTile>>5) land
                // at within-chunk cols quad*8 + si*4 + r2 (permutation, r0)
                uint2 pv;
                pv.x = packh2(acc[si][oj][0], acc[si][oj][1]);
                pv.y = packh2(acc[si][oj][2], acc[si][oj][3]);
                f16* dst = vh + ((((size_t)bh * 128 + (sTile >> 5)) * 32 + d) << 5)
                              + quad * 8 + si * 4;
                *reinterpret_cast<uint2*>(dst) = pv;
            } else {
                f16* dst = (which == 0 ? qt : kt) + (size_t)bh * HW * 32;
                #pragma unroll
                for (int r2 = 0; r2 < 4; ++r2)
                    dst[(size_t)(s2 + r2) * 32 + d] = (f16)acc[si][oj][r2];
            }
        }
}

// ---------------------------------------------------------------------------
// attn_mfma: MFMA flash attention, no-max softmax, split-K over j (4 splits).
// Zero LDS; VH chunk-tiled+permuted so exp values feed PV directly; all
// K/Q/V loads 1KB-coalesced (r11); A/B 2-chunk register sets (r10).
// r13: NSPLIT=4 -> 1024 blocks = 4/CU one generation (VGPR 60 -> cap 8/CU).
// Retests wave count with r9's uncoalesced-V confound removed.  Clean
// 1024-key spans = 16 double-chunk iters; span via min() stays opaque to
// the unroller (r8: unrolling -> VGPR 164).
// XCD-AFFINITY: 128 blocks/XCD = 4 (split,bh) combos x 32 q-blocks.
// NO launch_bounds min-occupancy arg (r2/r4: any hint -> spill storm).
// ---------------------------------------------------------------------------
#define MFMA16(A,B,C) __builtin_amdgcn_mfma_f32_16x16x32_f16(A,B,C,0,0,0)

#define LDKV(kd0,kd1,vd0,vd1,J)                                             \
    kd0 = ldg_f16x8(Kb + (size_t)((J) + q15) * 32 + quad * 8);              \
    kd1 = ldg_f16x8(Kb + (size_t)((J) + 16 + q15) * 32 + quad * 8);         \
    vd0 = ldg_f16x8(Vb + (((size_t)((J) >> 5) * 32 + q15) << 5) + quad * 8);\
    vd1 = ldg_f16x8(Vb + (((size_t)((J) >> 5) * 32 + 16 + q15) << 5) + quad * 8);

#define CHUNK(kf0_,kf1_,vf0_,vf1_)                                       \
    {                                                                    \
        const f32x4 z = {0.f, 0.f, 0.f, 0.f};                            \
        f32x4 s0a = MFMA16(kf0_, qf0, z);                                \
        f32x4 s1a = MFMA16(kf1_, qf0, z);                                \
        f32x4 s0b = MFMA16(kf0_, qf1, z);                                \
        f32x4 s1b = MFMA16(kf1_, qf1, z);                                \
        float ea[8], eb[8];                                              \
        _Pragma("unroll")                                                \
        for (int r = 0; r < 4; ++r) {                                    \
            ea[r]   = __builtin_amdgcn_exp2f(s0a[r]);                    \
            ea[4+r] = __builtin_amdgcn_exp2f(s1a[r]);                    \
            eb[r]   = __builtin_amdgcn_exp2f(s0b[r]);                    \
            eb[4+r] = __builtin_amdgcn_exp2f(s1b[r]);                    \
        }                                                                \
        l0 += (ea[0]+ea[1])+(ea[2]+ea[3])+(ea[4]+ea[5])+(ea[6]+ea[7]);   \
        l1 += (eb[0]+eb[1])+(eb[2]+eb[3])+(eb[4]+eb[5])+(eb[6]+eb[7]);   \
        union { unsigned u[4]; f16x8 v; } pa, pb;                        \
        pa.u[0] = packh2(ea[0], ea[1]); pa.u[1] = packh2(ea[2], ea[3]);  \
        pa.u[2] = packh2(ea[4], ea[5]); pa.u[3] = packh2(ea[6], ea[7]);  \
        pb.u[0] = packh2(eb[0], eb[1]); pb.u[1] = packh2(eb[2], eb[3]);  \
        pb.u[2] = packh2(eb[4], eb[5]); pb.u[3] = packh2(eb[6], eb[7]);  \
        acc[0][0] = MFMA16(vf0_, pa.v, acc[0][0]);                       \
        acc[0][1] = MFMA16(vf1_, pa.v, acc[0][1]);                       \
        acc[1][0] = MFMA16(vf0_, pb.v, acc[1][0]);                       \
        acc[1][1] = MFMA16(vf1_, pb.v, acc[1][1]);                       \
    }

__global__ __launch_bounds__(256) void attn_mfma(const f16* __restrict__ qt,
                                                 const f16* __restrict__ kt,
                                                 const f16* __restrict__ vh,
                                                 float* __restrict__ part) {
    const int w    = threadIdx.x >> 6;
    const int lane = threadIdx.x & 63;
    const int q15  = lane & 15;
    const int quad = lane >> 4;

    const int L    = blockIdx.x;          // 0..1023
    const int xcd  = L & 7;               // dispatch round-robin -> XCD id
    const int slot = L >> 3;              // 0..127 within XCD
    const int combo = xcd * 4 + (slot >> 5);   // 0..31 = (split,bh)
    const int qblk  = slot & 31;
    const int bh    = combo & 7;
    const int split = combo >> 3;              // 0..3
    const int qbase = (qblk * 4 + w) * 32;

    const f16* Qb = qt + (size_t)bh * HW * 32;
    const f16* Kb = kt + (size_t)bh * HW * 32;
    const f16* Vb = vh + (size_t)bh * 128 * 1024;   // [chunk][d][32] tiles

    f16x8 qf0 = ldg_f16x8(Qb + (size_t)(qbase + q15) * 32 + quad * 8);
    f16x8 qf1 = ldg_f16x8(Qb + (size_t)(qbase + 16 + q15) * 32 + quad * 8);

    f32x4 acc[2][2];
    #pragma unroll
    for (int a = 0; a < 2; ++a)
        #pragma unroll
        for (int b2 = 0; b2 < 2; ++b2)
            acc[a][b2] = (f32x4){0.f, 0.f, 0.f, 0.f};
    float l0 = 0.f, l1 = 0.f;

    const int j0   = split * 1024;
    const int span = min(1024, HW - j0);   // ==1024; opaque to unroller (r8)

    f16x8 ka0, ka1, va0, va1, kb0, kb1, vb0, vb1;
    LDKV(ka0, ka1, va0, va1, j0);
    LDKV(kb0, kb1, vb0, vb1, j0 + 32);

    for (int jc = 0; jc < span; jc += 64) {
        CHUNK(ka0, ka1, va0, va1);
        LDKV(ka0, ka1, va0, va1, j0 + jc + 64);   // last-iter prefetch reads
        CHUNK(kb0, kb1, vb0, vb1);                // past span: valid ws mem,
        LDKV(kb0, kb1, vb0, vb1, j0 + jc + 96);   // values unused
    }

    float* P = part + (size_t)split * 33 * ROWS_TOTAL;
    #pragma unroll
    for (int qb = 0; qb < 2; ++qb) {
        float lv = qb ? l1 : l0;
        lv += __shfl_xor(lv, 16, 64);
        lv += __shfl_xor(lv, 32, 64);
        const int grow = bh * HW + qbase + qb * 16 + q15;
        if (quad == 0) P[grow] = lv;
        #pragma unroll
        for (int t = 0; t < 2; ++t)
            #pragma unroll
            for (int r = 0; r < 4; ++r) {
                int d = t * 16 + quad * 4 + r;
                P[(size_t)(1 + d) * ROWS_TOTAL + grow] = acc[qb][t][r];
            }
    }
}

// ---------------------------------------------------------------------------
// attn_merge: sum NSPLIT additive splits, normalize, write HIDT (tiled).
// lane order: grow = blk*64 + (t&63), dq = t>>6 -> every PART load is 64
// consecutive grows = fully coalesced (r12).  36 loads + one 16B write.
// ---------------------------------------------------------------------------
__global__ __launch_bounds__(256) void attn_merge(const float* __restrict__ part,
                                                  f16* __restrict__ hidt) {
    const int grow = blockIdx.x * 64 + (threadIdx.x & 63);   // 0..32767
    const int dq   = threadIdx.x >> 6;                       // 0..3
    float l = 0.f;
    #pragma unroll
    for (int sp = 0; sp < NSPLIT; ++sp)
        l += part[(size_t)sp * 33 * ROWS_TOTAL + grow];
    const float inv = 1.0f / l;
    const int bh = grow >> 12, s = grow & 4095;
    const int b = bh >> 2, h = bh & 3;

    unsigned ov[4];
    #pragma unroll
    for (int i = 0; i < 4; ++i) {
        const int d2 = dq * 4 + i;
        float o0 = 0.f, o1 = 0.f;
        #pragma unroll
        for (int sp = 0; sp < NSPLIT; ++sp) {
            const float* P = part + (size_t)sp * 33 * ROWS_TOTAL + grow;
            o0 += P[(size_t)(1 + 2 * d2) * ROWS_TOTAL];
            o1 += P[(size_t)(2 + 2 * d2) * ROWS_TOTAL];
        }
        ov[i] = packh2(o0 * inv, o1 * inv);
    }
    // HIDT tiled [b][s/16][4][16][32]: c = h*32 + dq*8 -> k_tile = h
    f16* dst = hidt + ((((size_t)(b * 256 + (s >> 4))) * 4 + h) << 9)
                    + (s & 15) * 32 + dq * 8;
    *reinterpret_cast<uint4*>(dst) = make_uint4(ov[0], ov[1], ov[2], ov[3]);
}

// ---------------------------------------------------------------------------
// outp_mfma: out[b][o][s] = HIDT * WOH^T + bias  (f16 MFMA, K=128, fp32 out)
// HIDT/WOH tiled -> fragment loads are contiguous 1KB wave accesses.
// ---------------------------------------------------------------------------
__global__ __launch_bounds__(256) void outp_mfma(const f16* __restrict__ hidt,
                                                 const f16* __restrict__ woh,
                                                 const float* __restrict__ bout,
                                                 float* __restrict__ out) {
    const int w = threadIdx.x >> 6, lane = threadIdx.x & 63;
    const int q15 = lane & 15, quad = lane >> 4;
    const int b = blockIdx.z;
    const int sTile = blockIdx.x * 64 + (w & 1) * 32;
    const int oTile = blockIdx.y * 64 + (w >> 1) * 32;
    const f16* At = hidt + (((size_t)(b * 256 + (sTile >> 4))) << 11);  // *4 tiles *512
    const f16* Bt = woh + (((size_t)(oTile >> 4)) << 11);
    const int fo = q15 * 32 + quad * 8;

    f32x4 acc[2][2];
    #pragma unroll
    for (int i = 0; i < 2; ++i)
        #pragma unroll
        for (int j = 0; j < 2; ++j) acc[i][j] = (f32x4){0.f, 0.f, 0.f, 0.f};

    #pragma unroll
    for (int kc = 0; kc < 128; kc += 32) {
        const int kt5 = (kc >> 5) << 9;
        f16x8 a0 = ldg_f16x8(At + kt5 + fo);
        f16x8 a1 = ldg_f16x8(At + 2048 + kt5 + fo);
        f16x8 b0 = ldg_f16x8(Bt + kt5 + fo);
        f16x8 b1 = ldg_f16x8(Bt + 2048 + kt5 + fo);
        acc[0][0] = __builtin_amdgcn_mfma_f32_16x16x32_f16(a0, b0, acc[0][0], 0, 0, 0);
        acc[0][1] = __builtin_amdgcn_mfma_f32_16x16x32_f16(a0, b1, acc[0][1], 0, 0, 0);
        acc[1][0] = __builtin_amdgcn_mfma_f32_16x16x32_f16(a1, b0, acc[1][0], 0, 0, 0);
        acc[1][1] = __builtin_amdgcn_mfma_f32_16x16x32_f16(a1, b1, acc[1][1], 0, 0, 0);
    }

    #pragma unroll
    for (int oj = 0; oj < 2; ++oj) {
        const int o = oTile + oj * 16 + q15;
        const float bias = bout[o];
        #pragma unroll
        for (int si = 0; si < 2; ++si) {
            const int s2 = sTile + si * 16 + quad * 4;
            float4 v = make_float4(acc[si][oj][0] + bias, acc[si][oj][1] + bias,
                                   acc[si][oj][2] + bias, acc[si][oj][3] + bias);
            *reinterpret_cast<float4*>(out + ((size_t)(b * NC + o)) * HW + s2) = v;
        }
    }
}

// ---------------------------------------------------------------------------
extern "C" void kernel_launch(void* const* d_in, const int* in_sizes, int n_in,
                              void* d_out, int out_size, void* d_ws, size_t ws_size,
                              hipStream_t stream) {
    const float* x    = (const float*)d_in[0];
    const float* wqkv = (const float*)d_in[1];
    const float* wout = (const float*)d_in[2];
    const float* bout = (const float*)d_in[3];
    float* out = (float*)d_out;
    char* wsb  = (char*)d_ws;

    f16*   XT   = (f16*)(wsb + XT_OFF);
    f16*   QT   = (f16*)(wsb + QT_OFF);
    f16*   KT   = (f16*)(wsb + KT_OFF);
    f16*   VH   = (f16*)(wsb + VH_OFF);
    f16*   HIDT = (f16*)(wsb + HIDT_OFF);
    f16*   WQH  = (f16*)(wsb + WQH_OFF);
    f16*   WOH  = (f16*)(wsb + WOH_OFF);
    float* PART = (float*)(wsb + PART_OFF);

    prep     <<<dim3(640), 256, 0, stream>>>(x, wqkv, wout, XT, WQH, WOH);
    qkv_mfma <<<dim3(64, 6, NB), 256, 0, stream>>>(XT, WQH, QT, KT, VH);
    attn_mfma<<<dim3(1024), 256, 0, stream>>>(QT, KT, VH, PART);
    attn_merge<<<dim3(512), 256, 0, stream>>>(PART, HIDT);
    outp_mfma<<<dim3(64, 4, NB), 256, 0, stream>>>(HIDT, WOH, bout, out);
}

// Round 14
// 113.579 us; speedup vs baseline: 1.3797x; 1.0748x over previous
//
#include <hip/hip_runtime.h>

#define HEADS 4
#define DIM_HEAD 32
#define NB 2
#define NC 256
#define HW 4096
#define HIDDEN 128
#define NBH (NB*HEADS)
#define ROWS_TOTAL (NBH*HW)   // 32768

typedef _Float16 f16;
typedef _Float16 f16x8 __attribute__((ext_vector_type(8)));
typedef __fp16 fp16x2 __attribute__((ext_vector_type(2)));
typedef float f32x4 __attribute__((ext_vector_type(4)));

// workspace layout (bytes).  ALL mfma operand arrays are FRAGMENT-TILED:
// [row/16][k/32][16][32] f16 (1KB tiles) so every A/B fragment load
// (base + q15*32 + quad*8) is ONE contiguous 1KB wave access (r11/r12).
#define XT_OFF   0u                       // f16 [b][s/16][c/32=8][16][32]   4 MB
#define QT_OFF   (4u<<20)                 // f16 [bh][s][d32]     2 MB (rowstride 32 = coalesced)
#define KT_OFF   (6u<<20)                 // f16 [bh][s][d32]     2 MB
#define VH_OFF   (8u<<20)                 // f16 [bh][s/32][d32][32]  2 MB  (chunk-tiled, cols permuted)
#define HIDT_OFF (10u<<20)                // f16 [b][s/16][c/32=4][16][32]   2 MB
#define WQH_OFF  (12u<<20)                // f16 [384/16][256/32=8][16][32]  192 KB
#define WOH_OFF  ((12u<<20) + (256u<<10)) // f16 [256/16][128/32=4][16][32]  64 KB
// PART deleted (r14: split reduction fused into attn via LDS)

__device__ __forceinline__ f16x8 ldg_f16x8(const f16* p) {
    union { uint4 u; f16x8 v; } t;
    t.u = *reinterpret_cast<const uint4*>(p);
    return t.v;
}
__device__ __forceinline__ unsigned packh2(float a, float b) {
    union { fp16x2 h; unsigned u; } t;
    t.h = __builtin_amdgcn_cvt_pkrtz(a, b);
    return t.u;
}

// ---------------------------------------------------------------------------
// prep: FUSED wconv + xpose (independent preprocessing, block-partitioned).
// blocks 0..511: xpose  x[b][c][s] fp32 -> XT tiled [b][s/16][c/32][16][32]
// blocks 512..639: wconv -> WQH/WOH tiled
// ---------------------------------------------------------------------------
__global__ __launch_bounds__(256) void prep(const float* __restrict__ x,
                                            const float* __restrict__ wqkv,
                                            const float* __restrict__ wout,
                                            f16* __restrict__ xt,
                                            f16* __restrict__ wqh,
                                            f16* __restrict__ woh) {
    __shared__ float T[64][65];
    if (blockIdx.x < 512) {
        const int idx = blockIdx.x;
        const int b = idx >> 8, rem = idx & 255;
        const int c0 = (rem >> 6) * 64, s0 = (rem & 63) * 64;
        const int t = threadIdx.x;
        #pragma unroll
        for (int i = 0; i < 16; ++i) {
            int e = t + i * 256;
            int c = e >> 6, s = e & 63;
            T[c][s] = x[((size_t)(b * NC + c0 + c)) * HW + s0 + s];
        }
        __syncthreads();
        const int s = t >> 2, cg = (t & 3) * 16;
        unsigned ov[8];
        #pragma unroll
        for (int i = 0; i < 8; ++i)
            ov[i] = packh2(T[cg + 2 * i][s], T[cg + 2 * i + 1][s]);
        const int srow = s0 + s;
        f16* dst = xt + ((((size_t)(b * 256 + (srow >> 4))) * 8 + ((c0 + cg) >> 5)) << 9)
                      + (srow & 15) * 32 + (cg & 31);
        *reinterpret_cast<uint4*>(dst)     = make_uint4(ov[0], ov[1], ov[2], ov[3]);
        *reinterpret_cast<uint4*>(dst + 8) = make_uint4(ov[4], ov[5], ov[6], ov[7]);
        return;
    }
    const int tid = (blockIdx.x - 512) * 256 + threadIdx.x;
    const float QSCALE = 0.17677669529663687f * 1.4426950408889634f;
    if (tid < 24576) {                       // 384*256/4
        int o_lin = tid >> 6;
        int c4 = (tid & 63) * 4;
        int which = o_lin >> 7, r = o_lin & 127;
        int head = r >> 5, d = r & 31;
        int o_g = head * 96 + d * 3 + which;
        float4 v = *reinterpret_cast<const float4*>(wqkv + o_g * 256 + c4);
        float scl = (which == 0) ? QSCALE : 1.0f;
        uint2 pv;
        pv.x = packh2(v.x * scl, v.y * scl);
        pv.y = packh2(v.z * scl, v.w * scl);
        f16* dst = wqh + (((o_lin >> 4) * 8 + (c4 >> 5)) << 9)
                       + (o_lin & 15) * 32 + (c4 & 31);
        *reinterpret_cast<uint2*>(dst) = pv;
    } else if (tid < 24576 + 8192) {         // 256*128/4
        int t2 = tid - 24576;
        int o = t2 >> 5;                     // row in [0,256)
        int c4 = (t2 * 4) & 127;             // col in [0,128)
        float4 v = *reinterpret_cast<const float4*>(wout + t2 * 4);
        uint2 pv;
        pv.x = packh2(v.x, v.y);
        pv.y = packh2(v.z, v.w);
        f16* dst = woh + (((o >> 4) * 4 + (c4 >> 5)) << 9)
                       + (o & 15) * 32 + (c4 & 31);
        *reinterpret_cast<uint2*>(dst) = pv;
    }
}

// ---------------------------------------------------------------------------
// qkv_mfma: C[s][o_lin] = XT * WQH^T  (f16 MFMA, K=256).  XT/WQH tiled ->
// every fragment load is one contiguous 1KB wave access.
// VH chunk-tiled [bh][s/32][d][32] with per-chunk column permutation (r0/r11).
// ---------------------------------------------------------------------------
__global__ __launch_bounds__(256) void qkv_mfma(const f16* __restrict__ xt,
                                                const f16* __restrict__ wqh,
                                                f16* __restrict__ qt,
                                                f16* __restrict__ kt,
                                                f16* __restrict__ vh) {
    const int w = threadIdx.x >> 6, lane = threadIdx.x & 63;
    const int q15 = lane & 15, quad = lane >> 4;
    const int b = blockIdx.z;
    const int sTile = blockIdx.x * 64 + (w & 1) * 32;
    const int oTile = blockIdx.y * 64 + (w >> 1) * 32;
    const f16* At = xt + (((size_t)(b * 256 + (sTile >> 4))) << 12);  // *8 tiles *512
    const f16* Bt = wqh + (((size_t)(oTile >> 4)) << 12);
    const int fo = q15 * 32 + quad * 8;

    f32x4 acc[2][2];
    #pragma unroll
    for (int i = 0; i < 2; ++i)
        #pragma unroll
        for (int j = 0; j < 2; ++j) acc[i][j] = (f32x4){0.f, 0.f, 0.f, 0.f};

    #pragma unroll
    for (int kc = 0; kc < 256; kc += 32) {
        const int kt5 = (kc >> 5) << 9;
        f16x8 a0 = ldg_f16x8(At + kt5 + fo);
        f16x8 a1 = ldg_f16x8(At + 4096 + kt5 + fo);
        f16x8 b0 = ldg_f16x8(Bt + kt5 + fo);
        f16x8 b1 = ldg_f16x8(Bt + 4096 + kt5 + fo);
        acc[0][0] = __builtin_amdgcn_mfma_f32_16x16x32_f16(a0, b0, acc[0][0], 0, 0, 0);
        acc[0][1] = __builtin_amdgcn_mfma_f32_16x16x32_f16(a0, b1, acc[0][1], 0, 0, 0);
        acc[1][0] = __builtin_amdgcn_mfma_f32_16x16x32_f16(a1, b0, acc[1][0], 0, 0, 0);
        acc[1][1] = __builtin_amdgcn_mfma_f32_16x16x32_f16(a1, b1, acc[1][1], 0, 0, 0);
    }

    #pragma unroll
    for (int si = 0; si < 2; ++si)
        #pragma unroll
        for (int oj = 0; oj < 2; ++oj) {
            int o_lin = oTile + oj * 16 + q15;
            int which = o_lin >> 7;           // wave-uniform (tiles pure)
            int r = o_lin & 127;
            int head = r >> 5, d = r & 31;
            int bh = b * HEADS + head;
            int s2 = sTile + si * 16 + quad * 4;
            if (which == 2) {
                // keys s2..s2+3 (= si*16+quad*4+r2 within chunk sTile>>5) land
                // at within-chunk cols quad*8 + si*4 + r2 (permutation, r0)
                uint2 pv;
                pv.x = packh2(acc[si][oj][0], acc[si][oj][1]);
                pv.y = packh2(acc[si][oj][2], acc[si][oj][3]);
                f16* dst = vh + ((((size_t)bh * 128 + (sTile >> 5)) * 32 + d) << 5)
                              + quad * 8 + si * 4;
                *reinterpret_cast<uint2*>(dst) = pv;
            } else {
                f16* dst = (which == 0 ? qt : kt) + (size_t)bh * HW * 32;
                #pragma unroll
                for (int r2 = 0; r2 < 4; ++r2)
                    dst[(size_t)(s2 + r2) * 32 + d] = (f16)acc[si][oj][r2];
            }
        }
}

// ---------------------------------------------------------------------------
// attn_fused: MFMA flash attention WITH FUSED SPLIT REDUCTION (r14).
// One block = one 32-row q-tile; its 4 waves split the key axis (w*1024
// keys each, 16 double-chunk iters, r10/r11-proven inner loop).  After the
// main loop: acc -> LDS (16KB, b128), row-sums -> LDS, one barrier, 256
// threads sum the 4 partials, normalize, write the 2KB HIDT tile directly.
// Deletes PART (12.7-16.9MB write + ~19MB read) and the attn_merge kernel.
// XCD-AFFINITY: block L -> XCD L&7 = bh; each XCD owns ONE bh entirely
// (K+V+Q = 768KB, L2-resident).  Grid 1024 = 4 blocks/CU, one generation.
// NO launch_bounds min-occupancy arg (r2/r4: any hint -> spill storm).
// ---------------------------------------------------------------------------
#define MFMA16(A,B,C) __builtin_amdgcn_mfma_f32_16x16x32_f16(A,B,C,0,0,0)

#define LDKV(kd0,kd1,vd0,vd1,J)                                             \
    kd0 = ldg_f16x8(Kb + (size_t)((J) + q15) * 32 + quad * 8);              \
    kd1 = ldg_f16x8(Kb + (size_t)((J) + 16 + q15) * 32 + quad * 8);         \
    vd0 = ldg_f16x8(Vb + (((size_t)((J) >> 5) * 32 + q15) << 5) + quad * 8);\
    vd1 = ldg_f16x8(Vb + (((size_t)((J) >> 5) * 32 + 16 + q15) << 5) + quad * 8);

#define CHUNK(kf0_,kf1_,vf0_,vf1_)                                       \
    {                                                                    \
        const f32x4 z = {0.f, 0.f, 0.f, 0.f};                            \
        f32x4 s0a = MFMA16(kf0_, qf0, z);                                \
        f32x4 s1a = MFMA16(kf1_, qf0, z);                                \
        f32x4 s0b = MFMA16(kf0_, qf1, z);                                \
        f32x4 s1b = MFMA16(kf1_, qf1, z);                                \
        float ea[8], eb[8];                                              \
        _Pragma("unroll")                                                \
        for (int r = 0; r < 4; ++r) {                                    \
            ea[r]   = __builtin_amdgcn_exp2f(s0a[r]);                    \
            ea[4+r] = __builtin_amdgcn_exp2f(s1a[r]);                    \
            eb[r]   = __builtin_amdgcn_exp2f(s0b[r]);                    \
            eb[4+r] = __builtin_amdgcn_exp2f(s1b[r]);                    \
        }                                                                \
        l0 += (ea[0]+ea[1])+(ea[2]+ea[3])+(ea[4]+ea[5])+(ea[6]+ea[7]);   \
        l1 += (eb[0]+eb[1])+(eb[2]+eb[3])+(eb[4]+eb[5])+(eb[6]+eb[7]);   \
        union { unsigned u[4]; f16x8 v; } pa, pb;                        \
        pa.u[0] = packh2(ea[0], ea[1]); pa.u[1] = packh2(ea[2], ea[3]);  \
        pa.u[2] = packh2(ea[4], ea[5]); pa.u[3] = packh2(ea[6], ea[7]);  \
        pb.u[0] = packh2(eb[0], eb[1]); pb.u[1] = packh2(eb[2], eb[3]);  \
        pb.u[2] = packh2(eb[4], eb[5]); pb.u[3] = packh2(eb[6], eb[7]);  \
        acc[0][0] = MFMA16(vf0_, pa.v, acc[0][0]);                       \
        acc[0][1] = MFMA16(vf1_, pa.v, acc[0][1]);                       \
        acc[1][0] = MFMA16(vf0_, pb.v, acc[1][0]);                       \
        acc[1][1] = MFMA16(vf1_, pb.v, acc[1][1]);                       \
    }

__global__ __launch_bounds__(256) void attn_fused(const f16* __restrict__ qt,
                                                  const f16* __restrict__ kt,
                                                  const f16* __restrict__ vh,
                                                  f16* __restrict__ hidt) {
    __shared__ float Lo[4 * 4 * 256];   // [w][qb*2+t][lane*4+r]  16 KB
    __shared__ float Ll[4][2][16];      // [w][qb][q15] row-sums   512 B
    const int w    = threadIdx.x >> 6;
    const int lane = threadIdx.x & 63;
    const int q15  = lane & 15;
    const int quad = lane >> 4;

    const int L    = blockIdx.x;        // 0..1023
    const int bh   = L & 7;             // = XCD id (round-robin dispatch)
    const int qblk = L >> 3;            // 0..127
    const int qbase = qblk * 32;

    const f16* Qb = qt + (size_t)bh * HW * 32;
    const f16* Kb = kt + (size_t)bh * HW * 32;
    const f16* Vb = vh + (size_t)bh * 128 * 1024;   // [chunk][d][32] tiles

    f16x8 qf0 = ldg_f16x8(Qb + (size_t)(qbase + q15) * 32 + quad * 8);
    f16x8 qf1 = ldg_f16x8(Qb + (size_t)(qbase + 16 + q15) * 32 + quad * 8);

    f32x4 acc[2][2];
    #pragma unroll
    for (int a = 0; a < 2; ++a)
        #pragma unroll
        for (int b2 = 0; b2 < 2; ++b2)
            acc[a][b2] = (f32x4){0.f, 0.f, 0.f, 0.f};
    float l0 = 0.f, l1 = 0.f;

    const int j0   = w * 1024;                // wave = key-split
    const int span = min(1024, HW - j0);      // ==1024; opaque to unroller (r8)

    f16x8 ka0, ka1, va0, va1, kb0, kb1, vb0, vb1;
    LDKV(ka0, ka1, va0, va1, j0);
    LDKV(kb0, kb1, vb0, vb1, j0 + 32);

    for (int jc = 0; jc < span; jc += 64) {
        CHUNK(ka0, ka1, va0, va1);
        LDKV(ka0, ka1, va0, va1, j0 + jc + 64);   // last-iter prefetch reads
        CHUNK(kb0, kb1, vb0, vb1);                // past span: valid ws mem,
        LDKV(kb0, kb1, vb0, vb1, j0 + jc + 96);   // values unused
    }

    // per-wave row-sums: after two xors every lane holds its q-row's sum
    l0 += __shfl_xor(l0, 16, 64);
    l0 += __shfl_xor(l0, 32, 64);
    l1 += __shfl_xor(l1, 16, 64);
    l1 += __shfl_xor(l1, 32, 64);
    if (quad == 0) { Ll[w][0][q15] = l0; Ll[w][1][q15] = l1; }

    float* Wo = Lo + w * 1024;
    #pragma unroll
    for (int qb = 0; qb < 2; ++qb)
        #pragma unroll
        for (int t = 0; t < 2; ++t)
            *reinterpret_cast<f32x4*>(Wo + (qb * 2 + t) * 256 + lane * 4) = acc[qb][t];
    __syncthreads();

    // reduce 4 key-splits, normalize, write HIDT tile (2KB)
    const int row  = threadIdx.x >> 3;   // 0..31
    const int dg   = threadIdx.x & 7;    // 0..7
    const int qb   = row >> 4, q15r = row & 15;
    const int t_   = dg >> 2, quadr = dg & 3;
    const float l = Ll[0][qb][q15r] + Ll[1][qb][q15r] + Ll[2][qb][q15r] + Ll[3][qb][q15r];
    const float inv = 1.0f / l;
    float o0 = 0.f, o1 = 0.f, o2 = 0.f, o3 = 0.f;
    #pragma unroll
    for (int ww = 0; ww < 4; ++ww) {
        const float* p = Lo + ww * 1024 + (qb * 2 + t_) * 256 + (quadr * 16 + q15r) * 4;
        o0 += p[0]; o1 += p[1]; o2 += p[2]; o3 += p[3];
    }
    uint2 pv;
    pv.x = packh2(o0 * inv, o1 * inv);
    pv.y = packh2(o2 * inv, o3 * inv);
    const int s = qbase + row;
    const int b = bh >> 2, h = bh & 3;
    const int d = t_ * 16 + quadr * 4;
    f16* dst = hidt + ((((size_t)(b * 256 + (s >> 4))) * 4 + h) << 9)
                    + (s & 15) * 32 + d;
    *reinterpret_cast<uint2*>(dst) = pv;
}

// ---------------------------------------------------------------------------
// outp_mfma: out[b][o][s] = HIDT * WOH^T + bias  (f16 MFMA, K=128, fp32 out)
// HIDT/WOH tiled -> fragment loads are contiguous 1KB wave accesses.
// ---------------------------------------------------------------------------
__global__ __launch_bounds__(256) void outp_mfma(const f16* __restrict__ hidt,
                                                 const f16* __restrict__ woh,
                                                 const float* __restrict__ bout,
                                                 float* __restrict__ out) {
    const int w = threadIdx.x >> 6, lane = threadIdx.x & 63;
    const int q15 = lane & 15, quad = lane >> 4;
    const int b = blockIdx.z;
    const int sTile = blockIdx.x * 64 + (w & 1) * 32;
    const int oTile = blockIdx.y * 64 + (w >> 1) * 32;
    const f16* At = hidt + (((size_t)(b * 256 + (sTile >> 4))) << 11);  // *4 tiles *512
    const f16* Bt = woh + (((size_t)(oTile >> 4)) << 11);
    const int fo = q15 * 32 + quad * 8;

    f32x4 acc[2][2];
    #pragma unroll
    for (int i = 0; i < 2; ++i)
        #pragma unroll
        for (int j = 0; j < 2; ++j) acc[i][j] = (f32x4){0.f, 0.f, 0.f, 0.f};

    #pragma unroll
    for (int kc = 0; kc < 128; kc += 32) {
        const int kt5 = (kc >> 5) << 9;
        f16x8 a0 = ldg_f16x8(At + kt5 + fo);
        f16x8 a1 = ldg_f16x8(At + 2048 + kt5 + fo);
        f16x8 b0 = ldg_f16x8(Bt + kt5 + fo);
        f16x8 b1 = ldg_f16x8(Bt + 2048 + kt5 + fo);
        acc[0][0] = __builtin_amdgcn_mfma_f32_16x16x32_f16(a0, b0, acc[0][0], 0, 0, 0);
        acc[0][1] = __builtin_amdgcn_mfma_f32_16x16x32_f16(a0, b1, acc[0][1], 0, 0, 0);
        acc[1][0] = __builtin_amdgcn_mfma_f32_16x16x32_f16(a1, b0, acc[1][0], 0, 0, 0);
        acc[1][1] = __builtin_amdgcn_mfma_f32_16x16x32_f16(a1, b1, acc[1][1], 0, 0, 0);
    }

    #pragma unroll
    for (int oj = 0; oj < 2; ++oj) {
        const int o = oTile + oj * 16 + q15;
        const float bias = bout[o];
        #pragma unroll
        for (int si = 0; si < 2; ++si) {
            const int s2 = sTile + si * 16 + quad * 4;
            float4 v = make_float4(acc[si][oj][0] + bias, acc[si][oj][1] + bias,
                                   acc[si][oj][2] + bias, acc[si][oj][3] + bias);
            *reinterpret_cast<float4*>(out + ((size_t)(b * NC + o)) * HW + s2) = v;
        }
    }
}

// ---------------------------------------------------------------------------
extern "C" void kernel_launch(void* const* d_in, const int* in_sizes, int n_in,
                              void* d_out, int out_size, void* d_ws, size_t ws_size,
                              hipStream_t stream) {
    const float* x    = (const float*)d_in[0];
    const float* wqkv = (const float*)d_in[1];
    const float* wout = (const float*)d_in[2];
    const float* bout = (const float*)d_in[3];
    float* out = (float*)d_out;
    char* wsb  = (char*)d_ws;

    f16*   XT   = (f16*)(wsb + XT_OFF);
    f16*   QT   = (f16*)(wsb + QT_OFF);
    f16*   KT   = (f16*)(wsb + KT_OFF);
    f16*   VH   = (f16*)(wsb + VH_OFF);
    f16*   HIDT = (f16*)(wsb + HIDT_OFF);
    f16*   WQH  = (f16*)(wsb + WQH_OFF);
    f16*   WOH  = (f16*)(wsb + WOH_OFF);

    prep      <<<dim3(640), 256, 0, stream>>>(x, wqkv, wout, XT, WQH, WOH);
    qkv_mfma  <<<dim3(64, 6, NB), 256, 0, stream>>>(XT, WQH, QT, KT, VH);
    attn_fused<<<dim3(1024), 256, 0, stream>>>(QT, KT, VH, HIDT);
    outp_mfma <<<dim3(64, 4, NB), 256, 0, stream>>>(HIDT, WOH, bout, out);
}

// Round 15
// 113.194 us; speedup vs baseline: 1.3844x; 1.0034x over previous
//
#include <hip/hip_runtime.h>

#define HEADS 4
#define DIM_HEAD 32
#define NB 2
#define NC 256
#define HW 4096
#define HIDDEN 128
#define NBH (NB*HEADS)
#define ROWS_TOTAL (NBH*HW)   // 32768

typedef _Float16 f16;
typedef _Float16 f16x8 __attribute__((ext_vector_type(8)));
typedef __fp16 fp16x2 __attribute__((ext_vector_type(2)));
typedef float f32x4 __attribute__((ext_vector_type(4)));

// workspace layout (bytes).  ALL mfma operand arrays are FRAGMENT-TILED:
// [row/16][k/32][16][32] f16 (1KB tiles) so every A/B fragment load
// (base + q15*32 + quad*8) is ONE contiguous 1KB wave access (r11/r12).
#define XT_OFF   0u                       // f16 [b][s/16][c/32=8][16][32]   4 MB
#define QT_OFF   (4u<<20)                 // f16 [bh][s][d32]     2 MB (rowstride 32 = coalesced)
#define KT_OFF   (6u<<20)                 // f16 [bh][s][d32]     2 MB
#define VH_OFF   (8u<<20)                 // f16 [bh][s/32][d32][32]  2 MB  (chunk-tiled, cols permuted)
#define HIDT_OFF (10u<<20)                // f16 [b][s/16][c/32=4][16][32]   2 MB
#define WQH_OFF  (12u<<20)                // f16 [384/16][256/32=8][16][32]  192 KB
#define WOH_OFF  ((12u<<20) + (256u<<10)) // f16 [256/16][128/32=4][16][32]  64 KB
// PART deleted (r14: split reduction fused into attn via LDS)

__device__ __forceinline__ f16x8 ldg_f16x8(const f16* p) {
    union { uint4 u; f16x8 v; } t;
    t.u = *reinterpret_cast<const uint4*>(p);
    return t.v;
}
__device__ __forceinline__ unsigned packh2(float a, float b) {
    union { fp16x2 h; unsigned u; } t;
    t.h = __builtin_amdgcn_cvt_pkrtz(a, b);
    return t.u;
}

// ---------------------------------------------------------------------------
// prep: FUSED wconv + xpose (independent preprocessing, block-partitioned).
// blocks 0..511: xpose  x[b][c][s] fp32 -> XT tiled [b][s/16][c/32][16][32]
// blocks 512..639: wconv -> WQH/WOH tiled
// ---------------------------------------------------------------------------
__global__ __launch_bounds__(256) void prep(const float* __restrict__ x,
                                            const float* __restrict__ wqkv,
                                            const float* __restrict__ wout,
                                            f16* __restrict__ xt,
                                            f16* __restrict__ wqh,
                                            f16* __restrict__ woh) {
    __shared__ float T[64][65];
    if (blockIdx.x < 512) {
        const int idx = blockIdx.x;
        const int b = idx >> 8, rem = idx & 255;
        const int c0 = (rem >> 6) * 64, s0 = (rem & 63) * 64;
        const int t = threadIdx.x;
        #pragma unroll
        for (int i = 0; i < 16; ++i) {
            int e = t + i * 256;
            int c = e >> 6, s = e & 63;
            T[c][s] = x[((size_t)(b * NC + c0 + c)) * HW + s0 + s];
        }
        __syncthreads();
        const int s = t >> 2, cg = (t & 3) * 16;
        unsigned ov[8];
        #pragma unroll
        for (int i = 0; i < 8; ++i)
            ov[i] = packh2(T[cg + 2 * i][s], T[cg + 2 * i + 1][s]);
        const int srow = s0 + s;
        f16* dst = xt + ((((size_t)(b * 256 + (srow >> 4))) * 8 + ((c0 + cg) >> 5)) << 9)
                      + (srow & 15) * 32 + (cg & 31);
        *reinterpret_cast<uint4*>(dst)     = make_uint4(ov[0], ov[1], ov[2], ov[3]);
        *reinterpret_cast<uint4*>(dst + 8) = make_uint4(ov[4], ov[5], ov[6], ov[7]);
        return;
    }
    const int tid = (blockIdx.x - 512) * 256 + threadIdx.x;
    const float QSCALE = 0.17677669529663687f * 1.4426950408889634f;
    if (tid < 24576) {                       // 384*256/4
        int o_lin = tid >> 6;
        int c4 = (tid & 63) * 4;
        int which = o_lin >> 7, r = o_lin & 127;
        int head = r >> 5, d = r & 31;
        int o_g = head * 96 + d * 3 + which;
        float4 v = *reinterpret_cast<const float4*>(wqkv + o_g * 256 + c4);
        float scl = (which == 0) ? QSCALE : 1.0f;
        uint2 pv;
        pv.x = packh2(v.x * scl, v.y * scl);
        pv.y = packh2(v.z * scl, v.w * scl);
        f16* dst = wqh + (((o_lin >> 4) * 8 + (c4 >> 5)) << 9)
                       + (o_lin & 15) * 32 + (c4 & 31);
        *reinterpret_cast<uint2*>(dst) = pv;
    } else if (tid < 24576 + 8192) {         // 256*128/4
        int t2 = tid - 24576;
        int o = t2 >> 5;                     // row in [0,256)
        int c4 = (t2 * 4) & 127;             // col in [0,128)
        float4 v = *reinterpret_cast<const float4*>(wout + t2 * 4);
        uint2 pv;
        pv.x = packh2(v.x, v.y);
        pv.y = packh2(v.z, v.w);
        f16* dst = woh + (((o >> 4) * 4 + (c4 >> 5)) << 9)
                       + (o & 15) * 32 + (c4 & 31);
        *reinterpret_cast<uint2*>(dst) = pv;
    }
}

// ---------------------------------------------------------------------------
// qkv_mfma: C[s][o_lin] = XT * WQH^T  (f16 MFMA, K=256).  XT/WQH tiled ->
// every fragment load is one contiguous 1KB wave access.
// r15: K-loop A/B double-buffered (attn's r10 pattern): compute X MFMAs,
// issue X's next-iter loads, compute Y, issue Y's -- loads get ~1 full
// tile-compute of flight time instead of being consumed immediately.
// Last-iter prefetch reads <=10KB past XT/WQH into adjacent ws (valid,
// unused).  VH chunk-tiled [bh][s/32][d][32], cols permuted (r0/r11).
// ---------------------------------------------------------------------------
__global__ __launch_bounds__(256) void qkv_mfma(const f16* __restrict__ xt,
                                                const f16* __restrict__ wqh,
                                                f16* __restrict__ qt,
                                                f16* __restrict__ kt,
                                                f16* __restrict__ vh) {
    const int w = threadIdx.x >> 6, lane = threadIdx.x & 63;
    const int q15 = lane & 15, quad = lane >> 4;
    const int b = blockIdx.z;
    const int sTile = blockIdx.x * 64 + (w & 1) * 32;
    const int oTile = blockIdx.y * 64 + (w >> 1) * 32;
    const f16* At = xt + (((size_t)(b * 256 + (sTile >> 4))) << 12);  // *8 tiles *512
    const f16* Bt = wqh + (((size_t)(oTile >> 4)) << 12);
    const int fo = q15 * 32 + quad * 8;

    f32x4 acc[2][2];
    #pragma unroll
    for (int i = 0; i < 2; ++i)
        #pragma unroll
        for (int j = 0; j < 2; ++j) acc[i][j] = (f32x4){0.f, 0.f, 0.f, 0.f};

    f16x8 xa0 = ldg_f16x8(At + fo);
    f16x8 xa1 = ldg_f16x8(At + 4096 + fo);
    f16x8 xb0 = ldg_f16x8(Bt + fo);
    f16x8 xb1 = ldg_f16x8(Bt + 4096 + fo);
    f16x8 ya0 = ldg_f16x8(At + 512 + fo);
    f16x8 ya1 = ldg_f16x8(At + 4096 + 512 + fo);
    f16x8 yb0 = ldg_f16x8(Bt + 512 + fo);
    f16x8 yb1 = ldg_f16x8(Bt + 4096 + 512 + fo);

    #pragma unroll
    for (int kc = 0; kc < 256; kc += 64) {
        const int nx = (kc + 64) * 16;   // f16 offset of k-tile (kc+64)/32
        const int ny = (kc + 96) * 16;
        acc[0][0] = __builtin_amdgcn_mfma_f32_16x16x32_f16(xa0, xb0, acc[0][0], 0, 0, 0);
        acc[0][1] = __builtin_amdgcn_mfma_f32_16x16x32_f16(xa0, xb1, acc[0][1], 0, 0, 0);
        acc[1][0] = __builtin_amdgcn_mfma_f32_16x16x32_f16(xa1, xb0, acc[1][0], 0, 0, 0);
        acc[1][1] = __builtin_amdgcn_mfma_f32_16x16x32_f16(xa1, xb1, acc[1][1], 0, 0, 0);
        xa0 = ldg_f16x8(At + nx + fo);            // last-iter prefetch lands in
        xa1 = ldg_f16x8(At + 4096 + nx + fo);     // adjacent ws region (valid,
        xb0 = ldg_f16x8(Bt + nx + fo);            // unused)
        xb1 = ldg_f16x8(Bt + 4096 + nx + fo);
        acc[0][0] = __builtin_amdgcn_mfma_f32_16x16x32_f16(ya0, yb0, acc[0][0], 0, 0, 0);
        acc[0][1] = __builtin_amdgcn_mfma_f32_16x16x32_f16(ya0, yb1, acc[0][1], 0, 0, 0);
        acc[1][0] = __builtin_amdgcn_mfma_f32_16x16x32_f16(ya1, yb0, acc[1][0], 0, 0, 0);
        acc[1][1] = __builtin_amdgcn_mfma_f32_16x16x32_f16(ya1, yb1, acc[1][1], 0, 0, 0);
        ya0 = ldg_f16x8(At + ny + fo);
        ya1 = ldg_f16x8(At + 4096 + ny + fo);
        yb0 = ldg_f16x8(Bt + ny + fo);
        yb1 = ldg_f16x8(Bt + 4096 + ny + fo);
    }

    #pragma unroll
    for (int si = 0; si < 2; ++si)
        #pragma unroll
        for (int oj = 0; oj < 2; ++oj) {
            int o_lin = oTile + oj * 16 + q15;
            int which = o_lin >> 7;           // wave-uniform (tiles pure)
            int r = o_lin & 127;
            int head = r >> 5, d = r & 31;
            int bh = b * HEADS + head;
            int s2 = sTile + si * 16 + quad * 4;
            if (which == 2) {
                // keys s2..s2+3 (= si*16+quad*4+r2 within chunk sTile>>5) land
                // at within-chunk cols quad*8 + si*4 + r2 (permutation, r0)
                uint2 pv;
                pv.x = packh2(acc[si][oj][0], acc[si][oj][1]);
                pv.y = packh2(acc[si][oj][2], acc[si][oj][3]);
                f16* dst = vh + ((((size_t)bh * 128 + (sTile >> 5)) * 32 + d) << 5)
                              + quad * 8 + si * 4;
                *reinterpret_cast<uint2*>(dst) = pv;
            } else {
                f16* dst = (which == 0 ? qt : kt) + (size_t)bh * HW * 32;
                #pragma unroll
                for (int r2 = 0; r2 < 4; ++r2)
                    dst[(size_t)(s2 + r2) * 32 + d] = (f16)acc[si][oj][r2];
            }
        }
}

// ---------------------------------------------------------------------------
// attn_fused: MFMA flash attention WITH FUSED SPLIT REDUCTION (r14, frozen).
// One block = one 32-row q-tile; 4 waves split the key axis (w*1024 keys
// each, 16 double-chunk iters, r10/r11-proven inner loop).  Post-loop:
// acc -> LDS (16KB), row-sums -> LDS, barrier, 256 threads reduce 4
// partials, normalize, write the 2KB HIDT tile directly.
// XCD-AFFINITY: block L -> XCD L&7 = bh; each XCD owns ONE bh entirely.
// Grid 1024 = 4 blocks/CU, one generation.
// NO launch_bounds min-occupancy arg (r2/r4: any hint -> spill storm).
// ---------------------------------------------------------------------------
#define MFMA16(A,B,C) __builtin_amdgcn_mfma_f32_16x16x32_f16(A,B,C,0,0,0)

#define LDKV(kd0,kd1,vd0,vd1,J)                                             \
    kd0 = ldg_f16x8(Kb + (size_t)((J) + q15) * 32 + quad * 8);              \
    kd1 = ldg_f16x8(Kb + (size_t)((J) + 16 + q15) * 32 + quad * 8);         \
    vd0 = ldg_f16x8(Vb + (((size_t)((J) >> 5) * 32 + q15) << 5) + quad * 8);\
    vd1 = ldg_f16x8(Vb + (((size_t)((J) >> 5) * 32 + 16 + q15) << 5) + quad * 8);

#define CHUNK(kf0_,kf1_,vf0_,vf1_)                                       \
    {                                                                    \
        const f32x4 z = {0.f, 0.f, 0.f, 0.f};                            \
        f32x4 s0a = MFMA16(kf0_, qf0, z);                                \
        f32x4 s1a = MFMA16(kf1_, qf0, z);                                \
        f32x4 s0b = MFMA16(kf0_, qf1, z);                                \
        f32x4 s1b = MFMA16(kf1_, qf1, z);                                \
        float ea[8], eb[8];                                              \
        _Pragma("unroll")                                                \
        for (int r = 0; r < 4; ++r) {                                    \
            ea[r]   = __builtin_amdgcn_exp2f(s0a[r]);                    \
            ea[4+r] = __builtin_amdgcn_exp2f(s1a[r]);                    \
            eb[r]   = __builtin_amdgcn_exp2f(s0b[r]);                    \
            eb[4+r] = __builtin_amdgcn_exp2f(s1b[r]);                    \
        }                                                                \
        l0 += (ea[0]+ea[1])+(ea[2]+ea[3])+(ea[4]+ea[5])+(ea[6]+ea[7]);   \
        l1 += (eb[0]+eb[1])+(eb[2]+eb[3])+(eb[4]+eb[5])+(eb[6]+eb[7]);   \
        union { unsigned u[4]; f16x8 v; } pa, pb;                        \
        pa.u[0] = packh2(ea[0], ea[1]); pa.u[1] = packh2(ea[2], ea[3]);  \
        pa.u[2] = packh2(ea[4], ea[5]); pa.u[3] = packh2(ea[6], ea[7]);  \
        pb.u[0] = packh2(eb[0], eb[1]); pb.u[1] = packh2(eb[2], eb[3]);  \
        pb.u[2] = packh2(eb[4], eb[5]); pb.u[3] = packh2(eb[6], eb[7]);  \
        acc[0][0] = MFMA16(vf0_, pa.v, acc[0][0]);                       \
        acc[0][1] = MFMA16(vf1_, pa.v, acc[0][1]);                       \
        acc[1][0] = MFMA16(vf0_, pb.v, acc[1][0]);                       \
        acc[1][1] = MFMA16(vf1_, pb.v, acc[1][1]);                       \
    }

__global__ __launch_bounds__(256) void attn_fused(const f16* __restrict__ qt,
                                                  const f16* __restrict__ kt,
                                                  const f16* __restrict__ vh,
                                                  f16* __restrict__ hidt) {
    __shared__ float Lo[4 * 4 * 256];   // [w][qb*2+t][lane*4+r]  16 KB
    __shared__ float Ll[4][2][16];      // [w][qb][q15] row-sums   512 B
    const int w    = threadIdx.x >> 6;
    const int lane = threadIdx.x & 63;
    const int q15  = lane & 15;
    const int quad = lane >> 4;

    const int L    = blockIdx.x;        // 0..1023
    const int bh   = L & 7;             // = XCD id (round-robin dispatch)
    const int qblk = L >> 3;            // 0..127
    const int qbase = qblk * 32;

    const f16* Qb = qt + (size_t)bh * HW * 32;
    const f16* Kb = kt + (size_t)bh * HW * 32;
    const f16* Vb = vh + (size_t)bh * 128 * 1024;   // [chunk][d][32] tiles

    f16x8 qf0 = ldg_f16x8(Qb + (size_t)(qbase + q15) * 32 + quad * 8);
    f16x8 qf1 = ldg_f16x8(Qb + (size_t)(qbase + 16 + q15) * 32 + quad * 8);

    f32x4 acc[2][2];
    #pragma unroll
    for (int a = 0; a < 2; ++a)
        #pragma unroll
        for (int b2 = 0; b2 < 2; ++b2)
            acc[a][b2] = (f32x4){0.f, 0.f, 0.f, 0.f};
    float l0 = 0.f, l1 = 0.f;

    const int j0   = w * 1024;                // wave = key-split
    const int span = min(1024, HW - j0);      // ==1024; opaque to unroller (r8)

    f16x8 ka0, ka1, va0, va1, kb0, kb1, vb0, vb1;
    LDKV(ka0, ka1, va0, va1, j0);
    LDKV(kb0, kb1, vb0, vb1, j0 + 32);

    for (int jc = 0; jc < span; jc += 64) {
        CHUNK(ka0, ka1, va0, va1);
        LDKV(ka0, ka1, va0, va1, j0 + jc + 64);   // last-iter prefetch reads
        CHUNK(kb0, kb1, vb0, vb1);                // past span: valid ws mem,
        LDKV(kb0, kb1, vb0, vb1, j0 + jc + 96);   // values unused
    }

    // per-wave row-sums: after two xors every lane holds its q-row's sum
    l0 += __shfl_xor(l0, 16, 64);
    l0 += __shfl_xor(l0, 32, 64);
    l1 += __shfl_xor(l1, 16, 64);
    l1 += __shfl_xor(l1, 32, 64);
    if (quad == 0) { Ll[w][0][q15] = l0; Ll[w][1][q15] = l1; }

    float* Wo = Lo + w * 1024;
    #pragma unroll
    for (int qb = 0; qb < 2; ++qb)
        #pragma unroll
        for (int t = 0; t < 2; ++t)
            *reinterpret_cast<f32x4*>(Wo + (qb * 2 + t) * 256 + lane * 4) = acc[qb][t];
    __syncthreads();

    // reduce 4 key-splits, normalize, write HIDT tile (2KB)
    const int row  = threadIdx.x >> 3;   // 0..31
    const int dg   = threadIdx.x & 7;    // 0..7
    const int qb   = row >> 4, q15r = row & 15;
    const int t_   = dg >> 2, quadr = dg & 3;
    const float l = Ll[0][qb][q15r] + Ll[1][qb][q15r] + Ll[2][qb][q15r] + Ll[3][qb][q15r];
    const float inv = 1.0f / l;
    float o0 = 0.f, o1 = 0.f, o2 = 0.f, o3 = 0.f;
    #pragma unroll
    for (int ww = 0; ww < 4; ++ww) {
        const float* p = Lo + ww * 1024 + (qb * 2 + t_) * 256 + (quadr * 16 + q15r) * 4;
        o0 += p[0]; o1 += p[1]; o2 += p[2]; o3 += p[3];
    }
    uint2 pv;
    pv.x = packh2(o0 * inv, o1 * inv);
    pv.y = packh2(o2 * inv, o3 * inv);
    const int s = qbase + row;
    const int b = bh >> 2, h = bh & 3;
    const int d = t_ * 16 + quadr * 4;
    f16* dst = hidt + ((((size_t)(b * 256 + (s >> 4))) * 4 + h) << 9)
                    + (s & 15) * 32 + d;
    *reinterpret_cast<uint2*>(dst) = pv;
}

// ---------------------------------------------------------------------------
// outp_mfma: out[b][o][s] = HIDT * WOH^T + bias  (f16 MFMA, K=128, fp32 out)
// HIDT/WOH tiled -> fragment loads are contiguous 1KB wave accesses.
// r15: K-loop A/B double-buffered (same mechanism as qkv).  Last-iter
// prefetch reads <=6KB past HIDT/WOH into adjacent ws (valid, unused).
// ---------------------------------------------------------------------------
__global__ __launch_bounds__(256) void outp_mfma(const f16* __restrict__ hidt,
                                                 const f16* __restrict__ woh,
                                                 const float* __restrict__ bout,
                                                 float* __restrict__ out) {
    const int w = threadIdx.x >> 6, lane = threadIdx.x & 63;
    const int q15 = lane & 15, quad = lane >> 4;
    const int b = blockIdx.z;
    const int sTile = blockIdx.x * 64 + (w & 1) * 32;
    const int oTile = blockIdx.y * 64 + (w >> 1) * 32;
    const f16* At = hidt + (((size_t)(b * 256 + (sTile >> 4))) << 11);  // *4 tiles *512
    const f16* Bt = woh + (((size_t)(oTile >> 4)) << 11);
    const int fo = q15 * 32 + quad * 8;

    f32x4 acc[2][2];
    #pragma unroll
    for (int i = 0; i < 2; ++i)
        #pragma unroll
        for (int j = 0; j < 2; ++j) acc[i][j] = (f32x4){0.f, 0.f, 0.f, 0.f};

    f16x8 xa0 = ldg_f16x8(At + fo);
    f16x8 xa1 = ldg_f16x8(At + 2048 + fo);
    f16x8 xb0 = ldg_f16x8(Bt + fo);
    f16x8 xb1 = ldg_f16x8(Bt + 2048 + fo);
    f16x8 ya0 = ldg_f16x8(At + 512 + fo);
    f16x8 ya1 = ldg_f16x8(At + 2048 + 512 + fo);
    f16x8 yb0 = ldg_f16x8(Bt + 512 + fo);
    f16x8 yb1 = ldg_f16x8(Bt + 2048 + 512 + fo);

    #pragma unroll
    for (int kc = 0; kc < 128; kc += 64) {
        const int nx = (kc + 64) * 16;
        const int ny = (kc + 96) * 16;
        acc[0][0] = __builtin_amdgcn_mfma_f32_16x16x32_f16(xa0, xb0, acc[0][0], 0, 0, 0);
        acc[0][1] = __builtin_amdgcn_mfma_f32_16x16x32_f16(xa0, xb1, acc[0][1], 0, 0, 0);
        acc[1][0] = __builtin_amdgcn_mfma_f32_16x16x32_f16(xa1, xb0, acc[1][0], 0, 0, 0);
        acc[1][1] = __builtin_amdgcn_mfma_f32_16x16x32_f16(xa1, xb1, acc[1][1], 0, 0, 0);
        xa0 = ldg_f16x8(At + nx + fo);            // last-iter prefetch lands in
        xa1 = ldg_f16x8(At + 2048 + nx + fo);     // adjacent ws region (valid,
        xb0 = ldg_f16x8(Bt + nx + fo);            // unused)
        xb1 = ldg_f16x8(Bt + 2048 + nx + fo);
        acc[0][0] = __builtin_amdgcn_mfma_f32_16x16x32_f16(ya0, yb0, acc[0][0], 0, 0, 0);
        acc[0][1] = __builtin_amdgcn_mfma_f32_16x16x32_f16(ya0, yb1, acc[0][1], 0, 0, 0);
        acc[1][0] = __builtin_amdgcn_mfma_f32_16x16x32_f16(ya1, yb0, acc[1][0], 0, 0, 0);
        acc[1][1] = __builtin_amdgcn_mfma_f32_16x16x32_f16(ya1, yb1, acc[1][1], 0, 0, 0);
        ya0 = ldg_f16x8(At + ny + fo);
        ya1 = ldg_f16x8(At + 2048 + ny + fo);
        yb0 = ldg_f16x8(Bt + ny + fo);
        yb1 = ldg_f16x8(Bt + 2048 + ny + fo);
    }

    #pragma unroll
    for (int oj = 0; oj < 2; ++oj) {
        const int o = oTile + oj * 16 + q15;
        const float bias = bout[o];
        #pragma unroll
        for (int si = 0; si < 2; ++si) {
            const int s2 = sTile + si * 16 + quad * 4;
            float4 v = make_float4(acc[si][oj][0] + bias, acc[si][oj][1] + bias,
                                   acc[si][oj][2] + bias, acc[si][oj][3] + bias);
            *reinterpret_cast<float4*>(out + ((size_t)(b * NC + o)) * HW + s2) = v;
        }
    }
}

// ---------------------------------------------------------------------------
extern "C" void kernel_launch(void* const* d_in, const int* in_sizes, int n_in,
                              void* d_out, int out_size, void* d_ws, size_t ws_size,
                              hipStream_t stream) {
    const float* x    = (const float*)d_in[0];
    const float* wqkv = (const float*)d_in[1];
    const float* wout = (const float*)d_in[2];
    const float* bout = (const float*)d_in[3];
    float* out = (float*)d_out;
    char* wsb  = (char*)d_ws;

    f16*   XT   = (f16*)(wsb + XT_OFF);
    f16*   QT   = (f16*)(wsb + QT_OFF);
    f16*   KT   = (f16*)(wsb + KT_OFF);
    f16*   VH   = (f16*)(wsb + VH_OFF);
    f16*   HIDT = (f16*)(wsb + HIDT_OFF);
    f16*   WQH  = (f16*)(wsb + WQH_OFF);
    f16*   WOH  = (f16*)(wsb + WOH_OFF);

    prep      <<<dim3(640), 256, 0, stream>>>(x, wqkv, wout, XT, WQH, WOH);
    qkv_mfma  <<<dim3(64, 6, NB), 256, 0, stream>>>(XT, WQH, QT, KT, VH);
    attn_fused<<<dim3(1024), 256, 0, stream>>>(QT, KT, VH, HIDT);
    outp_mfma <<<dim3(64, 4, NB), 256, 0, stream>>>(HIDT, WOH, bout, out);
}